// Round 15
// baseline (440.017 us; speedup 1.0000x reference)
//
#include <hip/hip_runtime.h>
#include <hip/hip_bf16.h>

// Mamba2 mixer forward, MI355X gfx950. Round 15: chunk_cbl_y restructured for
// latency hiding — 512 threads/8 waves (16-row strips), fused B+C dual-acc loop
// (2x independent operand streams), LDS exp2f tables. All else frozen from r14.
// Shapes fixed: B=2 L=4096 dm=1024 di=2048 H=16 ds=hd=128 cs=128
#define NB 2
#define LSEQ 4096
#define DM 1024
#define DI 2048
#define NH 16
#define DSZ 128
#define CS 128
#define NCHUNK 32

using bf16 = __hip_bfloat16;
typedef __attribute__((ext_vector_type(8))) short short8;
typedef __attribute__((ext_vector_type(4))) float f32x4;

__device__ __forceinline__ float b2f(unsigned short u) {
    union { unsigned i; float f; } c; c.i = ((unsigned)u) << 16; return c.f;
}
__device__ __forceinline__ bf16 f2bf(float v) { return __float2bfloat16(v); }
__device__ __forceinline__ float bf2f(bf16 v) { return __bfloat162float(v); }

__device__ __forceinline__ float head_dt(const float* dt_bias, int h) {
    return log1pf(expf(dt_bias[h]));               // softplus
}
__device__ __forceinline__ float head_l2dec(const float* dt_bias, const float* A_log, int h, float* dt_out) {
    float dt = head_dt(dt_bias, h);
    *dt_out = dt;
    return -expf(A_log[h]) * dt * 1.4426950408889634f;   // log2(decay)
}

__device__ __forceinline__ void storeC(bf16* C, size_t idx, float v) { C[idx] = f2bf(v); }
__device__ __forceinline__ void storeC(float* C, size_t idx, float v) { C[idx] = v; }

// async global->LDS, 16B per lane; lds base wave-uniform (HW adds lane*16B)
__device__ __forceinline__ void gload16(const bf16* g, bf16* l) {
    __builtin_amdgcn_global_load_lds(
        (const __attribute__((address_space(1))) void*)g,
        (__attribute__((address_space(3))) void*)l, 16, 0, 0);
}

// ---------------- f32 -> bf16 cast
__global__ __launch_bounds__(256) void cast_f2b(const float* __restrict__ in,
                                                bf16* __restrict__ out, long n) {
    long i = ((long)blockIdx.x * 256 + threadIdx.x) * 8;
    if (i >= n) return;
    float4 a = *reinterpret_cast<const float4*>(in + i);
    float4 b = *reinterpret_cast<const float4*>(in + i + 4);
    union { bf16 h[8]; short8 v; } o;
    o.h[0] = f2bf(a.x); o.h[1] = f2bf(a.y); o.h[2] = f2bf(a.z); o.h[3] = f2bf(a.w);
    o.h[4] = f2bf(b.x); o.h[5] = f2bf(b.y); o.h[6] = f2bf(b.z); o.h[7] = f2bf(b.w);
    *reinterpret_cast<short8*>(out + i) = o.v;
}

// ---------------- 128x128 MFMA GEMM (r9-verified). MODE 1: col<DI->C0 else C1. MODE 2: C0.
template <int MODE, typename TO>
__global__ __launch_bounds__(256) void gemm_mfma(const bf16* __restrict__ A,
                                                 const bf16* __restrict__ W,
                                                 TO* __restrict__ C0, TO* __restrict__ C1,
                                                 int N, int K) {
    __shared__ bf16 As[2][128 * 32];
    __shared__ bf16 Ws[2][128 * 32];
    const int tid = threadIdx.x;
    const int lane = tid & 63, w = tid >> 6;
    const int wr = w >> 1, wc = w & 1;
    const int bm = blockIdx.y * 128, bn = blockIdx.x * 128;
    const int srow = lane >> 2;
    const int skoff = (((lane & 3) ^ ((lane >> 2) & 3)) * 8);
    const int g0 = w * 2, g1 = w * 2 + 1;
    const int fr = lane & 15;
    const int fk = (((lane >> 4) ^ (lane & 3)) * 8);
    f32x4 acc[4][4] = {};
#define STAGE(buf, kt)                                                                  \
    do {                                                                                \
        gload16(A + (size_t)(bm + g0 * 16 + srow) * K + (kt) + skoff, &As[buf][g0 * 512]); \
        gload16(A + (size_t)(bm + g1 * 16 + srow) * K + (kt) + skoff, &As[buf][g1 * 512]); \
        gload16(W + (size_t)(bn + g0 * 16 + srow) * K + (kt) + skoff, &Ws[buf][g0 * 512]); \
        gload16(W + (size_t)(bn + g1 * 16 + srow) * K + (kt) + skoff, &Ws[buf][g1 * 512]); \
    } while (0)
    STAGE(0, 0);
    __syncthreads();
    const int NT = K / 32;
    int cur = 0;
    for (int t = 0; t < NT; ++t) {
        if (t + 1 < NT) STAGE(cur ^ 1, (t + 1) * 32);
        short8 af[4], bfr[4];
#pragma unroll
        for (int mi = 0; mi < 4; ++mi)
            af[mi] = *reinterpret_cast<const short8*>(&As[cur][(wr * 64 + mi * 16 + fr) * 32 + fk]);
#pragma unroll
        for (int ni = 0; ni < 4; ++ni)
            bfr[ni] = *reinterpret_cast<const short8*>(&Ws[cur][(wc * 64 + ni * 16 + fr) * 32 + fk]);
#pragma unroll
        for (int mi = 0; mi < 4; ++mi)
#pragma unroll
            for (int ni = 0; ni < 4; ++ni)
                acc[mi][ni] = __builtin_amdgcn_mfma_f32_16x16x32_bf16(af[mi], bfr[ni], acc[mi][ni], 0, 0, 0);
        __syncthreads();
        cur ^= 1;
    }
#undef STAGE
    const int orow0 = (lane >> 4) * 4;
    const int ocol = lane & 15;
#pragma unroll
    for (int mi = 0; mi < 4; ++mi)
#pragma unroll
        for (int ni = 0; ni < 4; ++ni) {
            int col = bn + wc * 64 + ni * 16 + ocol;
#pragma unroll
            for (int r = 0; r < 4; ++r) {
                int row = bm + wr * 64 + mi * 16 + orow0 + r;
                float v = acc[mi][ni][r];
                if (MODE == 1) {
                    if (col < DI) storeC(C0, (size_t)row * DI + col, v);
                    else          storeC(C1, (size_t)row * DI + (col - DI), v);
                } else {
                    storeC(C0, (size_t)row * N + col, v);
                }
            }
        }
}

// ---------------- fused conv(K=4)+bias+SiLU+*dt+transpose -> XDT[d][j], per (chunk,head)
__global__ __launch_bounds__(256) void conv_xdt(const bf16* __restrict__ vpre,
                                                const float* __restrict__ cw,
                                                const float* __restrict__ cb,
                                                const float* __restrict__ dt_bias,
                                                bf16* __restrict__ XDT) {
    __shared__ bf16 Ts[131][136];
    __shared__ bf16 T2[128][136];
    __shared__ float wks[128][4];
    __shared__ float cbs[128];
    const int tid = threadIdx.x;
    const int bid = blockIdx.x;            // g*16 + h
    const int h = bid & 15, g = bid >> 4;  // g = b*32+n
    const int n31 = g & 31;
    const float dt = head_dt(dt_bias, h);
    if (tid < 128) {
        float4 w4 = *reinterpret_cast<const float4*>(cw + (h * 128 + tid) * 4);
        wks[tid][0] = w4.x; wks[tid][1] = w4.y; wks[tid][2] = w4.z; wks[tid][3] = w4.w;
        cbs[tid] = cb[h * 128 + tid];
    }
    {   // stage rows: local i in [0,131) <-> global row g*128-3+i (zero before batch start)
        const int lr = tid >> 4, c8 = (tid & 15) * 8;
        for (int i0 = 0; i0 < 144; i0 += 16) {
            int i = i0 + lr;
            if (i < 131) {
                short8 v = {0, 0, 0, 0, 0, 0, 0, 0};
                if (!(n31 == 0 && i < 3))
                    v = *reinterpret_cast<const short8*>(vpre + (size_t)(g * 128 - 3 + i) * 2048 + h * 128 + c8);
                *reinterpret_cast<short8*>(&Ts[i][c8]) = v;
            }
        }
    }
    __syncthreads();
    {   // conv + silu + *dt -> T2[j][d]
        const int jr = tid >> 4, d8 = (tid & 15) * 8;
        for (int j0 = 0; j0 < 128; j0 += 16) {
            int j = j0 + jr;
            union { bf16 hh[8]; short8 v; } o;
#pragma unroll
            for (int e = 0; e < 8; ++e) {
                int d = d8 + e;
                float s = cbs[d];
#pragma unroll
                for (int k = 0; k < 4; ++k) s += wks[d][k] * bf2f(Ts[j + k][d]);
                float sil = s / (1.f + expf(-s));
                o.hh[e] = f2bf(sil * dt);
            }
            *reinterpret_cast<short8*>(&T2[j][d8]) = o.v;
        }
    }
    __syncthreads();
    {   // transposed write XDT[ob + d*128 + j]
        const size_t ob = (size_t)bid * 16384;
        const int d = tid & 127;
        for (int jg = (tid >> 7); jg < 16; jg += 2) {
            int j0 = jg * 8;
            union { bf16 hh[8]; short8 v; } o;
#pragma unroll
            for (int e = 0; e < 8; ++e) o.hh[e] = T2[j0 + e][d];
            *reinterpret_cast<short8*>(XDT + ob + (size_t)d * 128 + j0) = o.v;
        }
    }
}

// ---------------- per-chunk transpose+scale: BT[s][j] = Bm[j,s]*dec^(127-j) (r9-verified)
__global__ __launch_bounds__(256) void transpose_bt(const bf16* __restrict__ in, bf16* __restrict__ outp,
                                                    const float* __restrict__ dt_bias,
                                                    const float* __restrict__ A_log) {
    __shared__ bf16 Ts[128][136];
    __shared__ float dpow[128];
    const int tid = threadIdx.x;
    const int bid = blockIdx.x;
    const int h = bid & 15, bn = bid >> 4;
    float dt; float l2d = head_l2dec(dt_bias, A_log, h, &dt);
    if (tid < 128) dpow[tid] = exp2f((float)(127 - tid) * l2d);
    const size_t base = (size_t)bn * CS * 2048 + (size_t)h * 128;
    {
        const int jr = tid >> 4, c8 = (tid & 15) * 8;
        for (int j0 = 0; j0 < 128; j0 += 16)
            *reinterpret_cast<short8*>(&Ts[j0 + jr][c8]) =
                *reinterpret_cast<const short8*>(in + base + (size_t)(j0 + jr) * 2048 + c8);
    }
    __syncthreads();
    const size_t ob = (size_t)bid * 16384;
    const int d = tid & 127;
    for (int jg = (tid >> 7); jg < 16; jg += 2) {
        int j0 = jg * 8;
        union { bf16 h8[8]; short8 v; } o;
#pragma unroll
        for (int e = 0; e < 8; ++e) o.h8[e] = f2bf(bf2f(Ts[j0 + e][d]) * dpow[j0 + e]);
        *reinterpret_cast<short8*>(outp + ob + (size_t)d * 128 + j0) = o.v;
    }
}

// ---------------- K1: STT[d][s] = sum_j XDT[d][j] * BT[s][j]  (STT may alias BT)
__global__ __launch_bounds__(256) void chunk_statesT(const bf16* __restrict__ XDT,
                                                     const bf16* BTg,
                                                     bf16* STT) {
    __shared__ bf16 XTs[128][72];
    __shared__ bf16 BTs[128][72];
    const int tid = threadIdx.x;
    const size_t ob = (size_t)blockIdx.x * 16384;
    const int lane = tid & 63, w = tid >> 6;
    const int fr = lane & 15, fk = (lane >> 4) * 8;
    f32x4 acc[2][8] = {};
    for (int j0 = 0; j0 < 128; j0 += 64) {
        for (int rr = 0; rr < 128; rr += 32) {
            int row = rr + (tid >> 3);
            int col = (tid & 7) * 8;
            *reinterpret_cast<short8*>(&XTs[row][col]) =
                *reinterpret_cast<const short8*>(XDT + ob + (size_t)row * 128 + j0 + col);
            *reinterpret_cast<short8*>(&BTs[row][col]) =
                *reinterpret_cast<const short8*>(BTg + ob + (size_t)row * 128 + j0 + col);
        }
        __syncthreads();
#pragma unroll
        for (int ks = 0; ks < 2; ++ks) {
            short8 a[2], bfr[8];
#pragma unroll
            for (int mi = 0; mi < 2; ++mi)
                a[mi] = *reinterpret_cast<const short8*>(&XTs[w * 32 + mi * 16 + fr][ks * 32 + fk]);
#pragma unroll
            for (int ni = 0; ni < 8; ++ni)
                bfr[ni] = *reinterpret_cast<const short8*>(&BTs[ni * 16 + fr][ks * 32 + fk]);
#pragma unroll
            for (int mi = 0; mi < 2; ++mi)
#pragma unroll
                for (int ni = 0; ni < 8; ++ni)
                    acc[mi][ni] = __builtin_amdgcn_mfma_f32_16x16x32_bf16(a[mi], bfr[ni], acc[mi][ni], 0, 0, 0);
        }
        __syncthreads();
    }
    const int orow0 = (lane >> 4) * 4, ocol = lane & 15;
#pragma unroll
    for (int mi = 0; mi < 2; ++mi)
#pragma unroll
        for (int ni = 0; ni < 8; ++ni) {
            int s = ni * 16 + ocol;
#pragma unroll
            for (int r = 0; r < 4; ++r) {
                int d = w * 32 + mi * 16 + orow0 + r;
                STT[ob + (size_t)d * 128 + s] = f2bf(acc[mi][ni][r]);
            }
        }
}

// ---------------- inter-chunk recurrence on STT (merged batches), in place
__global__ __launch_bounds__(256) void scan_kernel(bf16* __restrict__ ST,
                                                   const float* __restrict__ dt_bias,
                                                   const float* __restrict__ A_log) {
    const int q = blockIdx.x & 7;
    const int h = (blockIdx.x >> 3) & 15;
    const int b = blockIdx.x >> 7;
    float dt; float l2d = head_l2dec(dt_bias, A_log, h, &dt);
    float cd = exp2f(128.f * l2d);
    const int tid = threadIdx.x;
    float r[8] = {};
    for (int n = 0; n < NCHUNK; ++n) {
        size_t base = ((size_t)((b * NCHUNK + n) * NH + h)) * 16384 + (size_t)q * 2048;
#pragma unroll
        for (int e = 0; e < 8; ++e) {
            size_t idx = base + e * 256 + tid;
            float v = bf2f(ST[idx]);
            ST[idx] = f2bf(r[e]);
            r[e] = cd * r[e] + v;
        }
    }
}

// ---------------- merged: P = mask(C B^T); y = P@XDT + (C@STT)*dec^(i+1) + D*v; *silu(gate)
// 512 threads / 8 waves (wave = 16-row strip). Fused B+C dual-accumulator loop.
// LDS 37.9KB: phase-A staging [T1|Bst] aliased by P tile; exp2 tables dpw/dout.
__global__ __launch_bounds__(512) void chunk_cbl_y(const bf16* __restrict__ Bm, const bf16* __restrict__ Cm,
                                                   const bf16* __restrict__ STT, const bf16* __restrict__ XDT,
                                                   const float* __restrict__ dt_bias,
                                                   const float* __restrict__ A_log,
                                                   const float* __restrict__ D_param,
                                                   bf16* __restrict__ gateY) {
    __shared__ char smem[36864];
    __shared__ float dpw[128];
    __shared__ float dout[128];
    bf16 (*T1)[72]  = reinterpret_cast<bf16(*)[72]>(smem);           // phase A: C tile
    bf16 (*Bst)[72] = reinterpret_cast<bf16(*)[72]>(smem + 18432);   // phase A: B tile
    bf16 (*Ps)[136] = reinterpret_cast<bf16(*)[136]>(smem);          // after A: P (aliases both)
    const int tid = threadIdx.x;
    const int bid = blockIdx.x;
    const int h = bid & 15, g = bid >> 4;
    float dt; float l2d = head_l2dec(dt_bias, A_log, h, &dt);
    const size_t base = (size_t)g * CS * 2048 + (size_t)h * 128;
    const size_t ob = (size_t)bid * 16384;
    const int lane = tid & 63, w = tid >> 6;          // 8 waves
    const int w16 = w * 16;
    const int fr = lane & 15, fk = (lane >> 4) * 8;
    const int orow0 = (lane >> 4) * 4, ocol = lane & 15;
    const int strow = tid >> 3, stcol = (tid & 7) * 8;   // 64 rows x 64 cols per pass
    if (tid < 128) dpw[tid] = exp2f((float)tid * l2d);
    else if (tid < 256) dout[tid - 128] = exp2f((float)(tid - 127) * l2d);  // dec^(i+1)
    // ---- phase A: pacc = C B^T (wave strip w16..w16+15)
    f32x4 pacc[8] = {};
    for (int s0 = 0; s0 < 128; s0 += 64) {
        for (int rr = 0; rr < 128; rr += 64) {
            int row = rr + strow;
            *reinterpret_cast<short8*>(&T1[row][stcol]) =
                *reinterpret_cast<const short8*>(Cm + base + (size_t)row * 2048 + s0 + stcol);
            *reinterpret_cast<short8*>(&Bst[row][stcol]) =
                *reinterpret_cast<const short8*>(Bm + base + (size_t)row * 2048 + s0 + stcol);
        }
        __syncthreads();
#pragma unroll
        for (int ks = 0; ks < 2; ++ks) {
            short8 a = *reinterpret_cast<const short8*>(&T1[w16 + fr][ks * 32 + fk]);
            short8 bfr[8];
#pragma unroll
            for (int ni = 0; ni < 8; ++ni)
                bfr[ni] = *reinterpret_cast<const short8*>(&Bst[ni * 16 + fr][ks * 32 + fk]);
#pragma unroll
            for (int ni = 0; ni < 8; ++ni)
                pacc[ni] = __builtin_amdgcn_mfma_f32_16x16x32_bf16(a, bfr[ni], pacc[ni], 0, 0, 0);
        }
        __syncthreads();     // all waves done with T1/Bst before next stage / P overwrite
    }
    // ---- write P = mask*dpw into Ps (aliases staging; safe after barrier above)
#pragma unroll
    for (int ni = 0; ni < 8; ++ni) {
        int j = ni * 16 + ocol;
#pragma unroll
        for (int r = 0; r < 4; ++r) {
            int i = w16 + orow0 + r;
            float v = (i >= j) ? pacc[ni][r] * dpw[i - j] : 0.f;
            Ps[i][j] = f2bf(v);
        }
    }
    __syncthreads();         // publish P
    // ---- fused phases B+C: acc1 = C@STT, acc2 = P@XDT (independent operand streams)
    f32x4 acc1[8] = {}, acc2[8] = {};
#pragma unroll
    for (int ks = 0; ks < 4; ++ks) {
        short8 a1 = *reinterpret_cast<const short8*>(Cm + base + (size_t)(w16 + fr) * 2048 + ks * 32 + fk);
        short8 a2 = *reinterpret_cast<const short8*>(&Ps[w16 + fr][ks * 32 + fk]);
        short8 b1[8], b2[8];
#pragma unroll
        for (int ni = 0; ni < 8; ++ni)
            b1[ni] = *reinterpret_cast<const short8*>(STT + ob + (size_t)(ni * 16 + fr) * 128 + ks * 32 + fk);
#pragma unroll
        for (int ni = 0; ni < 8; ++ni)
            b2[ni] = *reinterpret_cast<const short8*>(XDT + ob + (size_t)(ni * 16 + fr) * 128 + ks * 32 + fk);
#pragma unroll
        for (int ni = 0; ni < 8; ++ni) {
            acc1[ni] = __builtin_amdgcn_mfma_f32_16x16x32_bf16(a1, b1[ni], acc1[ni], 0, 0, 0);
            acc2[ni] = __builtin_amdgcn_mfma_f32_16x16x32_bf16(a2, b2[ni], acc2[ni], 0, 0, 0);
        }
    }
    // ---- epilogue: y = (acc1*dec^(i+1) + acc2 + D*v) * silu(gate)
    const float Dv = D_param[h];
    const float inv_dt = 1.f / dt;
#pragma unroll
    for (int ni = 0; ni < 8; ++ni) {
        int d = ni * 16 + ocol;
#pragma unroll
        for (int r = 0; r < 4; ++r) {
            int i = w16 + orow0 + r;
            size_t idx = base + (size_t)i * 2048 + d;
            float v = bf2f(XDT[ob + (size_t)d * 128 + i]) * inv_dt;
            float yv = acc1[ni][r] * dout[i] + acc2[ni][r] + Dv * v;
            float gq = bf2f(gateY[idx]);
            gateY[idx] = f2bf(yv * gq / (1.f + expf(-gq)));
        }
    }
}

extern "C" void kernel_launch(void* const* d_in, const int* in_sizes, int n_in,
                              void* d_out, int out_size, void* d_ws, size_t ws_size,
                              hipStream_t stream) {
    (void)out_size;
    static const int exp_sizes[11] = {
        NB * LSEQ * DM, NB * LSEQ * DM, 2 * DI * DM, DI * 4, DI,
        NH * DSZ * DM, NH * DSZ * DM, NH, NH, NH, DM * DI
    };
    if (n_in != 11) return;
    for (int i = 0; i < 11; ++i) if (in_sizes[i] != exp_sizes[i]) return;

    const float* x         = (const float*)d_in[0];
    const float* x_prenorm = (const float*)d_in[1];
    const float* in_proj_w = (const float*)d_in[2];
    const float* conv_w    = (const float*)d_in[3];
    const float* conv_b    = (const float*)d_in[4];
    const float* B_proj_w  = (const float*)d_in[5];
    const float* C_proj_w  = (const float*)d_in[6];
    const float* dt_bias   = (const float*)d_in[7];
    const float* A_log     = (const float*)d_in[8];
    const float* D_param   = (const float*)d_in[9];
    const float* out_proj_w= (const float*)d_in[10];
    float* out = (float*)d_out;

    const size_t NE = (size_t)NB * LSEQ * DI;     // 16,777,216 elements
    const size_t SLOT = NE * 2;                   // 32 MiB
    if (ws_size < 5 * SLOT) return;               // 160 MiB (verified available)
    char* ws = (char*)d_ws;
    bf16* S0 = (bf16*)(ws);              // value_pre -> BT -> STT (in place)
    bf16* S1 = (bf16*)(ws + SLOT);       // gate -> y (in place)
    bf16* S2 = (bf16*)(ws + 2 * SLOT);   // XDT
    bf16* S3 = (bf16*)(ws + 3 * SLOT);   // w_in_b -> Bm -> w_out_b
    bf16* S4 = (bf16*)(ws + 4 * SLOT);   // Cm

    // d_out scratch: [xb | wBCb] until BC gemm done; then free until final output
    bf16* xb   = (bf16*)d_out;                         // 16.8 MB
    bf16* wBCb = (bf16*)((char*)d_out + 16777216);     // 8.4 MB

    const int M = NB * LSEQ;             // 8192
    const int NC = NB * NCHUNK * NH;     // 1024 chunk-blocks
    dim3 blk(256);

    // phase 1: in_proj
    cast_f2b<<<dim3(4096), blk, 0, stream>>>(x, xb, (long)NB * LSEQ * DM);
    cast_f2b<<<dim3(2048), blk, 0, stream>>>(in_proj_w, S3, (long)2 * DI * DM);
    gemm_mfma<1, bf16><<<dim3(2 * DI / 128, M / 128), blk, 0, stream>>>(xb, S3, S0, S1, 2 * DI, DM);
    // phase 2: fused conv+silu+dt+transpose -> XDT (S2); S0 (vpre) dead after
    conv_xdt<<<dim3(NC), blk, 0, stream>>>(S0, conv_w, conv_b, dt_bias, S2);
    // phase 3: merged B+C projection -> Bm (S3), Cm (S4)
    cast_f2b<<<dim3(4096), blk, 0, stream>>>(x_prenorm, xb, (long)NB * LSEQ * DM);
    cast_f2b<<<dim3(1024), blk, 0, stream>>>(B_proj_w, wBCb, (long)NH * DSZ * DM);
    cast_f2b<<<dim3(1024), blk, 0, stream>>>(C_proj_w, wBCb + (size_t)NH * DSZ * DM, (long)NH * DSZ * DM);
    gemm_mfma<1, bf16><<<dim3(2 * DI / 128, M / 128), blk, 0, stream>>>(xb, wBCb, S3, S4, 2 * DI, DM);
    // phase 3b: BT = scaled transpose of Bm -> S0 (coalesced LDS transpose)
    transpose_bt<<<dim3(NC), blk, 0, stream>>>(S3, S0, dt_bias, A_log);
    // phase 4: states (BT -> STT in place), inter-chunk scan
    chunk_statesT<<<dim3(NC), blk, 0, stream>>>(S2, S0, S0);
    scan_kernel<<<dim3(NB * NH * 8), blk, 0, stream>>>(S0, dt_bias, A_log);
    // phase 5: merged cbl + y (8 waves, fused B+C) -> y over gate (S1)
    chunk_cbl_y<<<dim3(NC), dim3(512), 0, stream>>>(S3, S4, S0, S2, dt_bias, A_log, D_param, S1);
    // phase 6: out_proj -> f32 d_out
    cast_f2b<<<dim3(1024), blk, 0, stream>>>(out_proj_w, S3, (long)DM * DI);
    gemm_mfma<2, float><<<dim3(DM / 128, M / 128), blk, 0, stream>>>(S1, S3, out, nullptr, DM, DI);
}

// Round 16
// 396.855 us; speedup vs baseline: 1.1088x; 1.1088x over previous
//
#include <hip/hip_runtime.h>
#include <hip/hip_bf16.h>

// Mamba2 mixer forward, MI355X gfx950. Round 16: revert to r12/r13 baseline;
// chunk_cbl_y phase-B STT staged via LDS (kill strided direct-global frags);
// XCD-aware block swizzle in gemm_mfma. Everything else = r12 verbatim.
// Shapes fixed: B=2 L=4096 dm=1024 di=2048 H=16 ds=hd=128 cs=128
#define NB 2
#define LSEQ 4096
#define DM 1024
#define DI 2048
#define NH 16
#define DSZ 128
#define CS 128
#define NCHUNK 32

using bf16 = __hip_bfloat16;
typedef __attribute__((ext_vector_type(8))) short short8;
typedef __attribute__((ext_vector_type(4))) float f32x4;

__device__ __forceinline__ float b2f(unsigned short u) {
    union { unsigned i; float f; } c; c.i = ((unsigned)u) << 16; return c.f;
}
__device__ __forceinline__ bf16 f2bf(float v) { return __float2bfloat16(v); }
__device__ __forceinline__ float bf2f(bf16 v) { return __bfloat162float(v); }

__device__ __forceinline__ float head_dt(const float* dt_bias, int h) {
    return log1pf(expf(dt_bias[h]));               // softplus
}
__device__ __forceinline__ float head_l2dec(const float* dt_bias, const float* A_log, int h, float* dt_out) {
    float dt = head_dt(dt_bias, h);
    *dt_out = dt;
    return -expf(A_log[h]) * dt * 1.4426950408889634f;   // log2(decay)
}

__device__ __forceinline__ void storeC(bf16* C, size_t idx, float v) { C[idx] = f2bf(v); }
__device__ __forceinline__ void storeC(float* C, size_t idx, float v) { C[idx] = v; }

// async global->LDS, 16B per lane; lds base wave-uniform (HW adds lane*16B)
__device__ __forceinline__ void gload16(const bf16* g, bf16* l) {
    __builtin_amdgcn_global_load_lds(
        (const __attribute__((address_space(1))) void*)g,
        (__attribute__((address_space(3))) void*)l, 16, 0, 0);
}

// ---------------- f32 -> bf16 cast
__global__ __launch_bounds__(256) void cast_f2b(const float* __restrict__ in,
                                                bf16* __restrict__ out, long n) {
    long i = ((long)blockIdx.x * 256 + threadIdx.x) * 8;
    if (i >= n) return;
    float4 a = *reinterpret_cast<const float4*>(in + i);
    float4 b = *reinterpret_cast<const float4*>(in + i + 4);
    union { bf16 h[8]; short8 v; } o;
    o.h[0] = f2bf(a.x); o.h[1] = f2bf(a.y); o.h[2] = f2bf(a.z); o.h[3] = f2bf(a.w);
    o.h[4] = f2bf(b.x); o.h[5] = f2bf(b.y); o.h[6] = f2bf(b.z); o.h[7] = f2bf(b.w);
    *reinterpret_cast<short8*>(out + i) = o.v;
}

// ---------------- 128x128 MFMA GEMM (r9-verified) + XCD swizzle.
// MODE 1: col<DI->C0 else C1. MODE 2: C0[m*N+n]. Grids must have nwg%8==0.
template <int MODE, typename TO>
__global__ __launch_bounds__(256) void gemm_mfma(const bf16* __restrict__ A,
                                                 const bf16* __restrict__ W,
                                                 TO* __restrict__ C0, TO* __restrict__ C1,
                                                 int N, int K) {
    __shared__ bf16 As[2][128 * 32];
    __shared__ bf16 Ws[2][128 * 32];
    const int tid = threadIdx.x;
    const int lane = tid & 63, w = tid >> 6;
    const int wr = w >> 1, wc = w & 1;
    // XCD-aware swizzle (T1): contiguous chunk of linear ids per XCD
    const unsigned nwgx = gridDim.x;
    const unsigned id = blockIdx.y * nwgx + blockIdx.x;
    const unsigned cpx = (nwgx * gridDim.y) >> 3;
    const unsigned sw = (id & 7) * cpx + (id >> 3);
    const int bm = (int)(sw / nwgx) * 128, bn = (int)(sw % nwgx) * 128;
    const int srow = lane >> 2;
    const int skoff = (((lane & 3) ^ ((lane >> 2) & 3)) * 8);
    const int g0 = w * 2, g1 = w * 2 + 1;
    const int fr = lane & 15;
    const int fk = (((lane >> 4) ^ (lane & 3)) * 8);
    f32x4 acc[4][4] = {};
#define STAGE(buf, kt)                                                                  \
    do {                                                                                \
        gload16(A + (size_t)(bm + g0 * 16 + srow) * K + (kt) + skoff, &As[buf][g0 * 512]); \
        gload16(A + (size_t)(bm + g1 * 16 + srow) * K + (kt) + skoff, &As[buf][g1 * 512]); \
        gload16(W + (size_t)(bn + g0 * 16 + srow) * K + (kt) + skoff, &Ws[buf][g0 * 512]); \
        gload16(W + (size_t)(bn + g1 * 16 + srow) * K + (kt) + skoff, &Ws[buf][g1 * 512]); \
    } while (0)
    STAGE(0, 0);
    __syncthreads();
    const int NT = K / 32;
    int cur = 0;
    for (int t = 0; t < NT; ++t) {
        if (t + 1 < NT) STAGE(cur ^ 1, (t + 1) * 32);
        short8 af[4], bfr[4];
#pragma unroll
        for (int mi = 0; mi < 4; ++mi)
            af[mi] = *reinterpret_cast<const short8*>(&As[cur][(wr * 64 + mi * 16 + fr) * 32 + fk]);
#pragma unroll
        for (int ni = 0; ni < 4; ++ni)
            bfr[ni] = *reinterpret_cast<const short8*>(&Ws[cur][(wc * 64 + ni * 16 + fr) * 32 + fk]);
#pragma unroll
        for (int mi = 0; mi < 4; ++mi)
#pragma unroll
            for (int ni = 0; ni < 4; ++ni)
                acc[mi][ni] = __builtin_amdgcn_mfma_f32_16x16x32_bf16(af[mi], bfr[ni], acc[mi][ni], 0, 0, 0);
        __syncthreads();
        cur ^= 1;
    }
#undef STAGE
    const int orow0 = (lane >> 4) * 4;
    const int ocol = lane & 15;
#pragma unroll
    for (int mi = 0; mi < 4; ++mi)
#pragma unroll
        for (int ni = 0; ni < 4; ++ni) {
            int col = bn + wc * 64 + ni * 16 + ocol;
#pragma unroll
            for (int r = 0; r < 4; ++r) {
                int row = bm + wr * 64 + mi * 16 + orow0 + r;
                float v = acc[mi][ni][r];
                if (MODE == 1) {
                    if (col < DI) storeC(C0, (size_t)row * DI + col, v);
                    else          storeC(C1, (size_t)row * DI + (col - DI), v);
                } else {
                    storeC(C0, (size_t)row * N + col, v);
                }
            }
        }
}

// ---------------- fused conv(K=4)+bias+SiLU+*dt+transpose -> XDT[d][j] (frozen r12)
__global__ __launch_bounds__(256) void conv_xdt(const bf16* __restrict__ vpre,
                                                const float* __restrict__ cw,
                                                const float* __restrict__ cb,
                                                const float* __restrict__ dt_bias,
                                                bf16* __restrict__ XDT) {
    __shared__ bf16 Ts[131][136];
    __shared__ bf16 T2[128][136];
    __shared__ float wks[128][4];
    __shared__ float cbs[128];
    const int tid = threadIdx.x;
    const int bid = blockIdx.x;            // g*16 + h
    const int h = bid & 15, g = bid >> 4;  // g = b*32+n
    const int n31 = g & 31;
    const float dt = head_dt(dt_bias, h);
    if (tid < 128) {
        float4 w4 = *reinterpret_cast<const float4*>(cw + (h * 128 + tid) * 4);
        wks[tid][0] = w4.x; wks[tid][1] = w4.y; wks[tid][2] = w4.z; wks[tid][3] = w4.w;
        cbs[tid] = cb[h * 128 + tid];
    }
    {
        const int lr = tid >> 4, c8 = (tid & 15) * 8;
        for (int i0 = 0; i0 < 144; i0 += 16) {
            int i = i0 + lr;
            if (i < 131) {
                short8 v = {0, 0, 0, 0, 0, 0, 0, 0};
                if (!(n31 == 0 && i < 3))
                    v = *reinterpret_cast<const short8*>(vpre + (size_t)(g * 128 - 3 + i) * 2048 + h * 128 + c8);
                *reinterpret_cast<short8*>(&Ts[i][c8]) = v;
            }
        }
    }
    __syncthreads();
    {
        const int jr = tid >> 4, d8 = (tid & 15) * 8;
        for (int j0 = 0; j0 < 128; j0 += 16) {
            int j = j0 + jr;
            union { bf16 hh[8]; short8 v; } o;
#pragma unroll
            for (int e = 0; e < 8; ++e) {
                int d = d8 + e;
                float s = cbs[d];
#pragma unroll
                for (int k = 0; k < 4; ++k) s += wks[d][k] * bf2f(Ts[j + k][d]);
                float sil = s / (1.f + expf(-s));
                o.hh[e] = f2bf(sil * dt);
            }
            *reinterpret_cast<short8*>(&T2[j][d8]) = o.v;
        }
    }
    __syncthreads();
    {
        const size_t ob = (size_t)bid * 16384;
        const int d = tid & 127;
        for (int jg = (tid >> 7); jg < 16; jg += 2) {
            int j0 = jg * 8;
            union { bf16 hh[8]; short8 v; } o;
#pragma unroll
            for (int e = 0; e < 8; ++e) o.hh[e] = T2[j0 + e][d];
            *reinterpret_cast<short8*>(XDT + ob + (size_t)d * 128 + j0) = o.v;
        }
    }
}

// ---------------- per-chunk transpose+scale: BT[s][j] = Bm[j,s]*dec^(127-j) (frozen r12)
__global__ __launch_bounds__(256) void transpose_bt(const bf16* __restrict__ in, bf16* __restrict__ outp,
                                                    const float* __restrict__ dt_bias,
                                                    const float* __restrict__ A_log) {
    __shared__ bf16 Ts[128][136];
    __shared__ float dpow[128];
    const int tid = threadIdx.x;
    const int bid = blockIdx.x;
    const int h = bid & 15, bn = bid >> 4;
    float dt; float l2d = head_l2dec(dt_bias, A_log, h, &dt);
    if (tid < 128) dpow[tid] = exp2f((float)(127 - tid) * l2d);
    const size_t base = (size_t)bn * CS * 2048 + (size_t)h * 128;
    {
        const int jr = tid >> 4, c8 = (tid & 15) * 8;
        for (int j0 = 0; j0 < 128; j0 += 16)
            *reinterpret_cast<short8*>(&Ts[j0 + jr][c8]) =
                *reinterpret_cast<const short8*>(in + base + (size_t)(j0 + jr) * 2048 + c8);
    }
    __syncthreads();
    const size_t ob = (size_t)bid * 16384;
    const int d = tid & 127;
    for (int jg = (tid >> 7); jg < 16; jg += 2) {
        int j0 = jg * 8;
        union { bf16 h8[8]; short8 v; } o;
#pragma unroll
        for (int e = 0; e < 8; ++e) o.h8[e] = f2bf(bf2f(Ts[j0 + e][d]) * dpow[j0 + e]);
        *reinterpret_cast<short8*>(outp + ob + (size_t)d * 128 + j0) = o.v;
    }
}

// ---------------- K1: STT[d][s] = sum_j XDT[d][j] * BT[s][j]  (frozen r12; STT may alias BT)
__global__ __launch_bounds__(256) void chunk_statesT(const bf16* __restrict__ XDT,
                                                     const bf16* BTg,
                                                     bf16* STT) {
    __shared__ bf16 XTs[128][72];
    __shared__ bf16 BTs[128][72];
    const int tid = threadIdx.x;
    const size_t ob = (size_t)blockIdx.x * 16384;
    const int lane = tid & 63, w = tid >> 6;
    const int fr = lane & 15, fk = (lane >> 4) * 8;
    f32x4 acc[2][8] = {};
    for (int j0 = 0; j0 < 128; j0 += 64) {
        for (int rr = 0; rr < 128; rr += 32) {
            int row = rr + (tid >> 3);
            int col = (tid & 7) * 8;
            *reinterpret_cast<short8*>(&XTs[row][col]) =
                *reinterpret_cast<const short8*>(XDT + ob + (size_t)row * 128 + j0 + col);
            *reinterpret_cast<short8*>(&BTs[row][col]) =
                *reinterpret_cast<const short8*>(BTg + ob + (size_t)row * 128 + j0 + col);
        }
        __syncthreads();
#pragma unroll
        for (int ks = 0; ks < 2; ++ks) {
            short8 a[2], bfr[8];
#pragma unroll
            for (int mi = 0; mi < 2; ++mi)
                a[mi] = *reinterpret_cast<const short8*>(&XTs[w * 32 + mi * 16 + fr][ks * 32 + fk]);
#pragma unroll
            for (int ni = 0; ni < 8; ++ni)
                bfr[ni] = *reinterpret_cast<const short8*>(&BTs[ni * 16 + fr][ks * 32 + fk]);
#pragma unroll
            for (int mi = 0; mi < 2; ++mi)
#pragma unroll
                for (int ni = 0; ni < 8; ++ni)
                    acc[mi][ni] = __builtin_amdgcn_mfma_f32_16x16x32_bf16(a[mi], bfr[ni], acc[mi][ni], 0, 0, 0);
        }
        __syncthreads();
    }
    const int orow0 = (lane >> 4) * 4, ocol = lane & 15;
#pragma unroll
    for (int mi = 0; mi < 2; ++mi)
#pragma unroll
        for (int ni = 0; ni < 8; ++ni) {
            int s = ni * 16 + ocol;
#pragma unroll
            for (int r = 0; r < 4; ++r) {
                int d = w * 32 + mi * 16 + orow0 + r;
                STT[ob + (size_t)d * 128 + s] = f2bf(acc[mi][ni][r]);
            }
        }
}

// ---------------- inter-chunk recurrence on STT (frozen r12)
__global__ __launch_bounds__(256) void scan_kernel(bf16* __restrict__ ST,
                                                   const float* __restrict__ dt_bias,
                                                   const float* __restrict__ A_log) {
    const int q = blockIdx.x & 7;
    const int h = (blockIdx.x >> 3) & 15;
    const int b = blockIdx.x >> 7;
    float dt; float l2d = head_l2dec(dt_bias, A_log, h, &dt);
    float cd = exp2f(128.f * l2d);
    const int tid = threadIdx.x;
    float r[8] = {};
    for (int n = 0; n < NCHUNK; ++n) {
        size_t base = ((size_t)((b * NCHUNK + n) * NH + h)) * 16384 + (size_t)q * 2048;
#pragma unroll
        for (int e = 0; e < 8; ++e) {
            size_t idx = base + e * 256 + tid;
            float v = bf2f(ST[idx]);
            ST[idx] = f2bf(r[e]);
            r[e] = cd * r[e] + v;
        }
    }
}

// ---------------- merged: P = mask(C B^T); y = P@XDT + (C@STT)*dec^(i+1) + D*v; *silu(gate)
// r13 LDS layout (T1 18432 + [Ps|Bst] alias 34816 = 53248). NEW: phase B's STT
// operand staged through T1 in two halves (coalesced) instead of direct-global frags.
__global__ __launch_bounds__(256) void chunk_cbl_y(const bf16* __restrict__ Bm, const bf16* __restrict__ Cm,
                                                   const bf16* __restrict__ STT, const bf16* __restrict__ XDT,
                                                   const float* __restrict__ dt_bias,
                                                   const float* __restrict__ A_log,
                                                   const float* __restrict__ D_param,
                                                   bf16* __restrict__ gateY) {
    __shared__ char smem[53248];
    bf16 (*T1)[72]  = reinterpret_cast<bf16(*)[72]>(smem);           // staging: C / STT / XDT halves
    bf16 (*Ps)[136] = reinterpret_cast<bf16(*)[136]>(smem + 18432);  // P (after phase A)
    bf16 (*Bst)[72] = reinterpret_cast<bf16(*)[72]>(smem + 18432);   // phase A B tile (aliases Ps)
    const int tid = threadIdx.x;
    const int bid = blockIdx.x;
    const int h = bid & 15, g = bid >> 4;
    float dt; float l2d = head_l2dec(dt_bias, A_log, h, &dt);
    const size_t base = (size_t)g * CS * 2048 + (size_t)h * 128;
    const size_t ob = (size_t)bid * 16384;
    const int lane = tid & 63, w = tid >> 6;
    const int fr = lane & 15, fk = (lane >> 4) * 8;
    const int orow0 = (lane >> 4) * 4, ocol = lane & 15;
    const int strow = tid >> 3, stcol = (tid & 7) * 8;   // staging coords (32 rows x 64 cols/pass)
    // ---- phase A: pacc = C B^T (C->T1, B->Bst per 64-col half)
    f32x4 pacc[2][8] = {};
    for (int s0 = 0; s0 < 128; s0 += 64) {
        for (int rr = 0; rr < 128; rr += 32) {
            int row = rr + strow;
            *reinterpret_cast<short8*>(&T1[row][stcol]) =
                *reinterpret_cast<const short8*>(Cm + base + (size_t)row * 2048 + s0 + stcol);
            *reinterpret_cast<short8*>(&Bst[row][stcol]) =
                *reinterpret_cast<const short8*>(Bm + base + (size_t)row * 2048 + s0 + stcol);
        }
        __syncthreads();
#pragma unroll
        for (int ks = 0; ks < 2; ++ks) {
            short8 a[2], bfr[8];
#pragma unroll
            for (int mi = 0; mi < 2; ++mi)
                a[mi] = *reinterpret_cast<const short8*>(&T1[w * 32 + mi * 16 + fr][ks * 32 + fk]);
#pragma unroll
            for (int ni = 0; ni < 8; ++ni)
                bfr[ni] = *reinterpret_cast<const short8*>(&Bst[ni * 16 + fr][ks * 32 + fk]);
#pragma unroll
            for (int mi = 0; mi < 2; ++mi)
#pragma unroll
                for (int ni = 0; ni < 8; ++ni)
                    pacc[mi][ni] = __builtin_amdgcn_mfma_f32_16x16x32_bf16(a[mi], bfr[ni], pacc[mi][ni], 0, 0, 0);
        }
        __syncthreads();     // all waves done with T1/Bst before P overwrites Bst
    }
    // ---- write P = mask*scale(pacc) into Ps (Bst dead)
#pragma unroll
    for (int mi = 0; mi < 2; ++mi)
#pragma unroll
        for (int ni = 0; ni < 8; ++ni) {
            int j = ni * 16 + ocol;
#pragma unroll
            for (int r = 0; r < 4; ++r) {
                int i = w * 32 + mi * 16 + orow0 + r;
                float v = (i >= j) ? pacc[mi][ni][r] * exp2f((float)(i - j) * l2d) : 0.f;
                Ps[i][j] = f2bf(v);
            }
        }
    // ---- phase B: acc = C @ STT; STT halves staged through T1 (coalesced)
    f32x4 acc[2][8] = {};
    for (int hk = 0; hk < 2; ++hk) {
        for (int rr = 0; rr < 128; rr += 32) {
            int row = rr + strow;
            *reinterpret_cast<short8*>(&T1[row][stcol]) =
                *reinterpret_cast<const short8*>(STT + ob + (size_t)row * 128 + hk * 64 + stcol);
        }
        __syncthreads();     // also publishes P on first pass
#pragma unroll
        for (int ks = 0; ks < 2; ++ks) {
            short8 a[2], bfr[8];
#pragma unroll
            for (int mi = 0; mi < 2; ++mi)
                a[mi] = *reinterpret_cast<const short8*>(Cm + base + (size_t)(w * 32 + mi * 16 + fr) * 2048 + hk * 64 + ks * 32 + fk);
#pragma unroll
            for (int ni = 0; ni < 8; ++ni)
                bfr[ni] = *reinterpret_cast<const short8*>(&T1[ni * 16 + fr][ks * 32 + fk]);
#pragma unroll
            for (int mi = 0; mi < 2; ++mi)
#pragma unroll
                for (int ni = 0; ni < 8; ++ni)
                    acc[mi][ni] = __builtin_amdgcn_mfma_f32_16x16x32_bf16(a[mi], bfr[ni], acc[mi][ni], 0, 0, 0);
        }
        __syncthreads();
    }
    // scale by decay_out = dec^(i+1)
#pragma unroll
    for (int mi = 0; mi < 2; ++mi)
#pragma unroll
        for (int r = 0; r < 4; ++r) {
            int i = w * 32 + mi * 16 + orow0 + r;
            float sc = exp2f((float)(i + 1) * l2d);
#pragma unroll
            for (int ni = 0; ni < 8; ++ni) acc[mi][ni][r] *= sc;
        }
    // ---- phase C: acc += P @ XDT (XDT halves staged through T1; A-op from Ps)
    for (int j0 = 0; j0 < 128; j0 += 64) {
        for (int rr = 0; rr < 128; rr += 32) {
            int row = rr + strow;
            *reinterpret_cast<short8*>(&T1[row][stcol]) =
                *reinterpret_cast<const short8*>(XDT + ob + (size_t)row * 128 + j0 + stcol);
        }
        __syncthreads();
#pragma unroll
        for (int ks = 0; ks < 2; ++ks) {
            short8 a[2], bfr[8];
#pragma unroll
            for (int mi = 0; mi < 2; ++mi)
                a[mi] = *reinterpret_cast<const short8*>(&Ps[w * 32 + mi * 16 + fr][j0 + ks * 32 + fk]);
#pragma unroll
            for (int ni = 0; ni < 8; ++ni)
                bfr[ni] = *reinterpret_cast<const short8*>(&T1[ni * 16 + fr][ks * 32 + fk]);
#pragma unroll
            for (int mi = 0; mi < 2; ++mi)
#pragma unroll
                for (int ni = 0; ni < 8; ++ni)
                    acc[mi][ni] = __builtin_amdgcn_mfma_f32_16x16x32_bf16(a[mi], bfr[ni], acc[mi][ni], 0, 0, 0);
        }
        __syncthreads();
    }
    // ---- epilogue: y = (acc + D*v) * silu(gate); v = XDT[d][i]/dt
    const float Dv = D_param[h];
    const float inv_dt = 1.f / dt;
#pragma unroll
    for (int mi = 0; mi < 2; ++mi)
#pragma unroll
        for (int ni = 0; ni < 8; ++ni) {
            int d = ni * 16 + ocol;
#pragma unroll
            for (int r = 0; r < 4; ++r) {
                int i = w * 32 + mi * 16 + orow0 + r;
                size_t idx = base + (size_t)i * 2048 + d;
                float v = bf2f(XDT[ob + (size_t)d * 128 + i]) * inv_dt;
                float yv = acc[mi][ni][r] + Dv * v;
                float gq = bf2f(gateY[idx]);
                gateY[idx] = f2bf(yv * gq / (1.f + expf(-gq)));
            }
        }
}

extern "C" void kernel_launch(void* const* d_in, const int* in_sizes, int n_in,
                              void* d_out, int out_size, void* d_ws, size_t ws_size,
                              hipStream_t stream) {
    (void)out_size;
    static const int exp_sizes[11] = {
        NB * LSEQ * DM, NB * LSEQ * DM, 2 * DI * DM, DI * 4, DI,
        NH * DSZ * DM, NH * DSZ * DM, NH, NH, NH, DM * DI
    };
    if (n_in != 11) return;
    for (int i = 0; i < 11; ++i) if (in_sizes[i] != exp_sizes[i]) return;

    const float* x         = (const float*)d_in[0];
    const float* x_prenorm = (const float*)d_in[1];
    const float* in_proj_w = (const float*)d_in[2];
    const float* conv_w    = (const float*)d_in[3];
    const float* conv_b    = (const float*)d_in[4];
    const float* B_proj_w  = (const float*)d_in[5];
    const float* C_proj_w  = (const float*)d_in[6];
    const float* dt_bias   = (const float*)d_in[7];
    const float* A_log     = (const float*)d_in[8];
    const float* D_param   = (const float*)d_in[9];
    const float* out_proj_w= (const float*)d_in[10];
    float* out = (float*)d_out;

    const size_t NE = (size_t)NB * LSEQ * DI;     // 16,777,216 elements
    const size_t SLOT = NE * 2;                   // 32 MiB
    if (ws_size < 5 * SLOT) return;               // 160 MiB (verified available)
    char* ws = (char*)d_ws;
    bf16* S0 = (bf16*)(ws);              // value_pre -> BT -> STT (in place)
    bf16* S1 = (bf16*)(ws + SLOT);       // gate -> y (in place)
    bf16* S2 = (bf16*)(ws + 2 * SLOT);   // XDT
    bf16* S3 = (bf16*)(ws + 3 * SLOT);   // w_in_b -> Bm -> w_out_b
    bf16* S4 = (bf16*)(ws + 4 * SLOT);   // Cm

    // d_out scratch: [xb | wBCb] until BC gemm done; then free until final output
    bf16* xb   = (bf16*)d_out;                         // 16.8 MB
    bf16* wBCb = (bf16*)((char*)d_out + 16777216);     // 8.4 MB

    const int M = NB * LSEQ;             // 8192
    const int NC = NB * NCHUNK * NH;     // 1024 chunk-blocks
    dim3 blk(256);

    // phase 1: in_proj
    cast_f2b<<<dim3(4096), blk, 0, stream>>>(x, xb, (long)NB * LSEQ * DM);
    cast_f2b<<<dim3(2048), blk, 0, stream>>>(in_proj_w, S3, (long)2 * DI * DM);
    gemm_mfma<1, bf16><<<dim3(2 * DI / 128, M / 128), blk, 0, stream>>>(xb, S3, S0, S1, 2 * DI, DM);
    // phase 2: fused conv+silu+dt+transpose -> XDT (S2); S0 (vpre) dead after
    conv_xdt<<<dim3(NC), blk, 0, stream>>>(S0, conv_w, conv_b, dt_bias, S2);
    // phase 3: merged B+C projection -> Bm (S3), Cm (S4)
    cast_f2b<<<dim3(4096), blk, 0, stream>>>(x_prenorm, xb, (long)NB * LSEQ * DM);
    cast_f2b<<<dim3(1024), blk, 0, stream>>>(B_proj_w, wBCb, (long)NH * DSZ * DM);
    cast_f2b<<<dim3(1024), blk, 0, stream>>>(C_proj_w, wBCb + (size_t)NH * DSZ * DM, (long)NH * DSZ * DM);
    gemm_mfma<1, bf16><<<dim3(2 * DI / 128, M / 128), blk, 0, stream>>>(xb, wBCb, S3, S4, 2 * DI, DM);
    // phase 3b: BT = scaled transpose of Bm -> S0 (coalesced LDS transpose)
    transpose_bt<<<dim3(NC), blk, 0, stream>>>(S3, S0, dt_bias, A_log);
    // phase 4: states (BT -> STT in place), inter-chunk scan
    chunk_statesT<<<dim3(NC), blk, 0, stream>>>(S2, S0, S0);
    scan_kernel<<<dim3(NB * NH * 8), blk, 0, stream>>>(S0, dt_bias, A_log);
    // phase 5: merged cbl + y -> y over gate (S1)
    chunk_cbl_y<<<dim3(NC), blk, 0, stream>>>(S3, S4, S0, S2, dt_bias, A_log, D_param, S1);
    // phase 6: out_proj -> f32 d_out
    cast_f2b<<<dim3(1024), blk, 0, stream>>>(out_proj_w, S3, (long)DM * DI);
    gemm_mfma<2, float><<<dim3(DM / 128, M / 128), blk, 0, stream>>>(S1, S3, out, nullptr, DM, DI);
}

// Round 17
// 385.697 us; speedup vs baseline: 1.1408x; 1.0289x over previous
//
#include <hip/hip_runtime.h>
#include <hip/hip_bf16.h>

// Mamba2 mixer forward, MI355X gfx950. Round 17: r16 minus the XCD swizzle
// (FETCH +37% evidence) plus T5 s_setprio around MFMA clusters in the
// multi-phase chunk kernels (statesT, cbl_y). Everything else = r16 verbatim.
// Shapes fixed: B=2 L=4096 dm=1024 di=2048 H=16 ds=hd=128 cs=128
#define NB 2
#define LSEQ 4096
#define DM 1024
#define DI 2048
#define NH 16
#define DSZ 128
#define CS 128
#define NCHUNK 32

using bf16 = __hip_bfloat16;
typedef __attribute__((ext_vector_type(8))) short short8;
typedef __attribute__((ext_vector_type(4))) float f32x4;

__device__ __forceinline__ float b2f(unsigned short u) {
    union { unsigned i; float f; } c; c.i = ((unsigned)u) << 16; return c.f;
}
__device__ __forceinline__ bf16 f2bf(float v) { return __float2bfloat16(v); }
__device__ __forceinline__ float bf2f(bf16 v) { return __bfloat162float(v); }

__device__ __forceinline__ float head_dt(const float* dt_bias, int h) {
    return log1pf(expf(dt_bias[h]));               // softplus
}
__device__ __forceinline__ float head_l2dec(const float* dt_bias, const float* A_log, int h, float* dt_out) {
    float dt = head_dt(dt_bias, h);
    *dt_out = dt;
    return -expf(A_log[h]) * dt * 1.4426950408889634f;   // log2(decay)
}

__device__ __forceinline__ void storeC(bf16* C, size_t idx, float v) { C[idx] = f2bf(v); }
__device__ __forceinline__ void storeC(float* C, size_t idx, float v) { C[idx] = v; }

// async global->LDS, 16B per lane; lds base wave-uniform (HW adds lane*16B)
__device__ __forceinline__ void gload16(const bf16* g, bf16* l) {
    __builtin_amdgcn_global_load_lds(
        (const __attribute__((address_space(1))) void*)g,
        (__attribute__((address_space(3))) void*)l, 16, 0, 0);
}

// ---------------- f32 -> bf16 cast
__global__ __launch_bounds__(256) void cast_f2b(const float* __restrict__ in,
                                                bf16* __restrict__ out, long n) {
    long i = ((long)blockIdx.x * 256 + threadIdx.x) * 8;
    if (i >= n) return;
    float4 a = *reinterpret_cast<const float4*>(in + i);
    float4 b = *reinterpret_cast<const float4*>(in + i + 4);
    union { bf16 h[8]; short8 v; } o;
    o.h[0] = f2bf(a.x); o.h[1] = f2bf(a.y); o.h[2] = f2bf(a.z); o.h[3] = f2bf(a.w);
    o.h[4] = f2bf(b.x); o.h[5] = f2bf(b.y); o.h[6] = f2bf(b.z); o.h[7] = f2bf(b.w);
    *reinterpret_cast<short8*>(out + i) = o.v;
}

// ---------------- 128x128 MFMA GEMM (r9/r12-verified, linear block mapping).
// MODE 1: col<DI->C0 else C1. MODE 2: C0[m*N+n].
template <int MODE, typename TO>
__global__ __launch_bounds__(256) void gemm_mfma(const bf16* __restrict__ A,
                                                 const bf16* __restrict__ W,
                                                 TO* __restrict__ C0, TO* __restrict__ C1,
                                                 int N, int K) {
    __shared__ bf16 As[2][128 * 32];
    __shared__ bf16 Ws[2][128 * 32];
    const int tid = threadIdx.x;
    const int lane = tid & 63, w = tid >> 6;
    const int wr = w >> 1, wc = w & 1;
    const int bm = blockIdx.y * 128, bn = blockIdx.x * 128;
    const int srow = lane >> 2;
    const int skoff = (((lane & 3) ^ ((lane >> 2) & 3)) * 8);
    const int g0 = w * 2, g1 = w * 2 + 1;
    const int fr = lane & 15;
    const int fk = (((lane >> 4) ^ (lane & 3)) * 8);
    f32x4 acc[4][4] = {};
#define STAGE(buf, kt)                                                                  \
    do {                                                                                \
        gload16(A + (size_t)(bm + g0 * 16 + srow) * K + (kt) + skoff, &As[buf][g0 * 512]); \
        gload16(A + (size_t)(bm + g1 * 16 + srow) * K + (kt) + skoff, &As[buf][g1 * 512]); \
        gload16(W + (size_t)(bn + g0 * 16 + srow) * K + (kt) + skoff, &Ws[buf][g0 * 512]); \
        gload16(W + (size_t)(bn + g1 * 16 + srow) * K + (kt) + skoff, &Ws[buf][g1 * 512]); \
    } while (0)
    STAGE(0, 0);
    __syncthreads();
    const int NT = K / 32;
    int cur = 0;
    for (int t = 0; t < NT; ++t) {
        if (t + 1 < NT) STAGE(cur ^ 1, (t + 1) * 32);
        short8 af[4], bfr[4];
#pragma unroll
        for (int mi = 0; mi < 4; ++mi)
            af[mi] = *reinterpret_cast<const short8*>(&As[cur][(wr * 64 + mi * 16 + fr) * 32 + fk]);
#pragma unroll
        for (int ni = 0; ni < 4; ++ni)
            bfr[ni] = *reinterpret_cast<const short8*>(&Ws[cur][(wc * 64 + ni * 16 + fr) * 32 + fk]);
#pragma unroll
        for (int mi = 0; mi < 4; ++mi)
#pragma unroll
            for (int ni = 0; ni < 4; ++ni)
                acc[mi][ni] = __builtin_amdgcn_mfma_f32_16x16x32_bf16(af[mi], bfr[ni], acc[mi][ni], 0, 0, 0);
        __syncthreads();
        cur ^= 1;
    }
#undef STAGE
    const int orow0 = (lane >> 4) * 4;
    const int ocol = lane & 15;
#pragma unroll
    for (int mi = 0; mi < 4; ++mi)
#pragma unroll
        for (int ni = 0; ni < 4; ++ni) {
            int col = bn + wc * 64 + ni * 16 + ocol;
#pragma unroll
            for (int r = 0; r < 4; ++r) {
                int row = bm + wr * 64 + mi * 16 + orow0 + r;
                float v = acc[mi][ni][r];
                if (MODE == 1) {
                    if (col < DI) storeC(C0, (size_t)row * DI + col, v);
                    else          storeC(C1, (size_t)row * DI + (col - DI), v);
                } else {
                    storeC(C0, (size_t)row * N + col, v);
                }
            }
        }
}

// ---------------- fused conv(K=4)+bias+SiLU+*dt+transpose -> XDT[d][j] (frozen r12)
__global__ __launch_bounds__(256) void conv_xdt(const bf16* __restrict__ vpre,
                                                const float* __restrict__ cw,
                                                const float* __restrict__ cb,
                                                const float* __restrict__ dt_bias,
                                                bf16* __restrict__ XDT) {
    __shared__ bf16 Ts[131][136];
    __shared__ bf16 T2[128][136];
    __shared__ float wks[128][4];
    __shared__ float cbs[128];
    const int tid = threadIdx.x;
    const int bid = blockIdx.x;            // g*16 + h
    const int h = bid & 15, g = bid >> 4;  // g = b*32+n
    const int n31 = g & 31;
    const float dt = head_dt(dt_bias, h);
    if (tid < 128) {
        float4 w4 = *reinterpret_cast<const float4*>(cw + (h * 128 + tid) * 4);
        wks[tid][0] = w4.x; wks[tid][1] = w4.y; wks[tid][2] = w4.z; wks[tid][3] = w4.w;
        cbs[tid] = cb[h * 128 + tid];
    }
    {
        const int lr = tid >> 4, c8 = (tid & 15) * 8;
        for (int i0 = 0; i0 < 144; i0 += 16) {
            int i = i0 + lr;
            if (i < 131) {
                short8 v = {0, 0, 0, 0, 0, 0, 0, 0};
                if (!(n31 == 0 && i < 3))
                    v = *reinterpret_cast<const short8*>(vpre + (size_t)(g * 128 - 3 + i) * 2048 + h * 128 + c8);
                *reinterpret_cast<short8*>(&Ts[i][c8]) = v;
            }
        }
    }
    __syncthreads();
    {
        const int jr = tid >> 4, d8 = (tid & 15) * 8;
        for (int j0 = 0; j0 < 128; j0 += 16) {
            int j = j0 + jr;
            union { bf16 hh[8]; short8 v; } o;
#pragma unroll
            for (int e = 0; e < 8; ++e) {
                int d = d8 + e;
                float s = cbs[d];
#pragma unroll
                for (int k = 0; k < 4; ++k) s += wks[d][k] * bf2f(Ts[j + k][d]);
                float sil = s / (1.f + expf(-s));
                o.hh[e] = f2bf(sil * dt);
            }
            *reinterpret_cast<short8*>(&T2[j][d8]) = o.v;
        }
    }
    __syncthreads();
    {
        const size_t ob = (size_t)bid * 16384;
        const int d = tid & 127;
        for (int jg = (tid >> 7); jg < 16; jg += 2) {
            int j0 = jg * 8;
            union { bf16 hh[8]; short8 v; } o;
#pragma unroll
            for (int e = 0; e < 8; ++e) o.hh[e] = T2[j0 + e][d];
            *reinterpret_cast<short8*>(XDT + ob + (size_t)d * 128 + j0) = o.v;
        }
    }
}

// ---------------- per-chunk transpose+scale: BT[s][j] = Bm[j,s]*dec^(127-j) (frozen r12)
__global__ __launch_bounds__(256) void transpose_bt(const bf16* __restrict__ in, bf16* __restrict__ outp,
                                                    const float* __restrict__ dt_bias,
                                                    const float* __restrict__ A_log) {
    __shared__ bf16 Ts[128][136];
    __shared__ float dpow[128];
    const int tid = threadIdx.x;
    const int bid = blockIdx.x;
    const int h = bid & 15, bn = bid >> 4;
    float dt; float l2d = head_l2dec(dt_bias, A_log, h, &dt);
    if (tid < 128) dpow[tid] = exp2f((float)(127 - tid) * l2d);
    const size_t base = (size_t)bn * CS * 2048 + (size_t)h * 128;
    {
        const int jr = tid >> 4, c8 = (tid & 15) * 8;
        for (int j0 = 0; j0 < 128; j0 += 16)
            *reinterpret_cast<short8*>(&Ts[j0 + jr][c8]) =
                *reinterpret_cast<const short8*>(in + base + (size_t)(j0 + jr) * 2048 + c8);
    }
    __syncthreads();
    const size_t ob = (size_t)bid * 16384;
    const int d = tid & 127;
    for (int jg = (tid >> 7); jg < 16; jg += 2) {
        int j0 = jg * 8;
        union { bf16 h8[8]; short8 v; } o;
#pragma unroll
        for (int e = 0; e < 8; ++e) o.h8[e] = f2bf(bf2f(Ts[j0 + e][d]) * dpow[j0 + e]);
        *reinterpret_cast<short8*>(outp + ob + (size_t)d * 128 + j0) = o.v;
    }
}

// ---------------- K1: STT[d][s] = sum_j XDT[d][j] * BT[s][j]  (+T5 setprio)
__global__ __launch_bounds__(256) void chunk_statesT(const bf16* __restrict__ XDT,
                                                     const bf16* BTg,
                                                     bf16* STT) {
    __shared__ bf16 XTs[128][72];
    __shared__ bf16 BTs[128][72];
    const int tid = threadIdx.x;
    const size_t ob = (size_t)blockIdx.x * 16384;
    const int lane = tid & 63, w = tid >> 6;
    const int fr = lane & 15, fk = (lane >> 4) * 8;
    f32x4 acc[2][8] = {};
    for (int j0 = 0; j0 < 128; j0 += 64) {
        for (int rr = 0; rr < 128; rr += 32) {
            int row = rr + (tid >> 3);
            int col = (tid & 7) * 8;
            *reinterpret_cast<short8*>(&XTs[row][col]) =
                *reinterpret_cast<const short8*>(XDT + ob + (size_t)row * 128 + j0 + col);
            *reinterpret_cast<short8*>(&BTs[row][col]) =
                *reinterpret_cast<const short8*>(BTg + ob + (size_t)row * 128 + j0 + col);
        }
        __syncthreads();
        __builtin_amdgcn_s_setprio(1);
#pragma unroll
        for (int ks = 0; ks < 2; ++ks) {
            short8 a[2], bfr[8];
#pragma unroll
            for (int mi = 0; mi < 2; ++mi)
                a[mi] = *reinterpret_cast<const short8*>(&XTs[w * 32 + mi * 16 + fr][ks * 32 + fk]);
#pragma unroll
            for (int ni = 0; ni < 8; ++ni)
                bfr[ni] = *reinterpret_cast<const short8*>(&BTs[ni * 16 + fr][ks * 32 + fk]);
#pragma unroll
            for (int mi = 0; mi < 2; ++mi)
#pragma unroll
                for (int ni = 0; ni < 8; ++ni)
                    acc[mi][ni] = __builtin_amdgcn_mfma_f32_16x16x32_bf16(a[mi], bfr[ni], acc[mi][ni], 0, 0, 0);
        }
        __builtin_amdgcn_s_setprio(0);
        __syncthreads();
    }
    const int orow0 = (lane >> 4) * 4, ocol = lane & 15;
#pragma unroll
    for (int mi = 0; mi < 2; ++mi)
#pragma unroll
        for (int ni = 0; ni < 8; ++ni) {
            int s = ni * 16 + ocol;
#pragma unroll
            for (int r = 0; r < 4; ++r) {
                int d = w * 32 + mi * 16 + orow0 + r;
                STT[ob + (size_t)d * 128 + s] = f2bf(acc[mi][ni][r]);
            }
        }
}

// ---------------- inter-chunk recurrence on STT (frozen r12)
__global__ __launch_bounds__(256) void scan_kernel(bf16* __restrict__ ST,
                                                   const float* __restrict__ dt_bias,
                                                   const float* __restrict__ A_log) {
    const int q = blockIdx.x & 7;
    const int h = (blockIdx.x >> 3) & 15;
    const int b = blockIdx.x >> 7;
    float dt; float l2d = head_l2dec(dt_bias, A_log, h, &dt);
    float cd = exp2f(128.f * l2d);
    const int tid = threadIdx.x;
    float r[8] = {};
    for (int n = 0; n < NCHUNK; ++n) {
        size_t base = ((size_t)((b * NCHUNK + n) * NH + h)) * 16384 + (size_t)q * 2048;
#pragma unroll
        for (int e = 0; e < 8; ++e) {
            size_t idx = base + e * 256 + tid;
            float v = bf2f(ST[idx]);
            ST[idx] = f2bf(r[e]);
            r[e] = cd * r[e] + v;
        }
    }
}

// ---------------- merged: P = mask(C B^T); y = P@XDT + (C@STT)*dec^(i+1) + D*v; *silu(gate)
// r16 structure (STT/XDT staged via T1) + T5 setprio around MFMA clusters.
__global__ __launch_bounds__(256) void chunk_cbl_y(const bf16* __restrict__ Bm, const bf16* __restrict__ Cm,
                                                   const bf16* __restrict__ STT, const bf16* __restrict__ XDT,
                                                   const float* __restrict__ dt_bias,
                                                   const float* __restrict__ A_log,
                                                   const float* __restrict__ D_param,
                                                   bf16* __restrict__ gateY) {
    __shared__ char smem[53248];
    bf16 (*T1)[72]  = reinterpret_cast<bf16(*)[72]>(smem);           // staging: C / STT / XDT halves
    bf16 (*Ps)[136] = reinterpret_cast<bf16(*)[136]>(smem + 18432);  // P (after phase A)
    bf16 (*Bst)[72] = reinterpret_cast<bf16(*)[72]>(smem + 18432);   // phase A B tile (aliases Ps)
    const int tid = threadIdx.x;
    const int bid = blockIdx.x;
    const int h = bid & 15, g = bid >> 4;
    float dt; float l2d = head_l2dec(dt_bias, A_log, h, &dt);
    const size_t base = (size_t)g * CS * 2048 + (size_t)h * 128;
    const size_t ob = (size_t)bid * 16384;
    const int lane = tid & 63, w = tid >> 6;
    const int fr = lane & 15, fk = (lane >> 4) * 8;
    const int orow0 = (lane >> 4) * 4, ocol = lane & 15;
    const int strow = tid >> 3, stcol = (tid & 7) * 8;
    // ---- phase A: pacc = C B^T
    f32x4 pacc[2][8] = {};
    for (int s0 = 0; s0 < 128; s0 += 64) {
        for (int rr = 0; rr < 128; rr += 32) {
            int row = rr + strow;
            *reinterpret_cast<short8*>(&T1[row][stcol]) =
                *reinterpret_cast<const short8*>(Cm + base + (size_t)row * 2048 + s0 + stcol);
            *reinterpret_cast<short8*>(&Bst[row][stcol]) =
                *reinterpret_cast<const short8*>(Bm + base + (size_t)row * 2048 + s0 + stcol);
        }
        __syncthreads();
        __builtin_amdgcn_s_setprio(1);
#pragma unroll
        for (int ks = 0; ks < 2; ++ks) {
            short8 a[2], bfr[8];
#pragma unroll
            for (int mi = 0; mi < 2; ++mi)
                a[mi] = *reinterpret_cast<const short8*>(&T1[w * 32 + mi * 16 + fr][ks * 32 + fk]);
#pragma unroll
            for (int ni = 0; ni < 8; ++ni)
                bfr[ni] = *reinterpret_cast<const short8*>(&Bst[ni * 16 + fr][ks * 32 + fk]);
#pragma unroll
            for (int mi = 0; mi < 2; ++mi)
#pragma unroll
                for (int ni = 0; ni < 8; ++ni)
                    pacc[mi][ni] = __builtin_amdgcn_mfma_f32_16x16x32_bf16(a[mi], bfr[ni], pacc[mi][ni], 0, 0, 0);
        }
        __builtin_amdgcn_s_setprio(0);
        __syncthreads();
    }
    // ---- write P = mask*scale(pacc) into Ps (Bst dead)
#pragma unroll
    for (int mi = 0; mi < 2; ++mi)
#pragma unroll
        for (int ni = 0; ni < 8; ++ni) {
            int j = ni * 16 + ocol;
#pragma unroll
            for (int r = 0; r < 4; ++r) {
                int i = w * 32 + mi * 16 + orow0 + r;
                float v = (i >= j) ? pacc[mi][ni][r] * exp2f((float)(i - j) * l2d) : 0.f;
                Ps[i][j] = f2bf(v);
            }
        }
    // ---- phase B: acc = C @ STT; STT halves staged through T1
    f32x4 acc[2][8] = {};
    for (int hk = 0; hk < 2; ++hk) {
        for (int rr = 0; rr < 128; rr += 32) {
            int row = rr + strow;
            *reinterpret_cast<short8*>(&T1[row][stcol]) =
                *reinterpret_cast<const short8*>(STT + ob + (size_t)row * 128 + hk * 64 + stcol);
        }
        __syncthreads();
        __builtin_amdgcn_s_setprio(1);
#pragma unroll
        for (int ks = 0; ks < 2; ++ks) {
            short8 a[2], bfr[8];
#pragma unroll
            for (int mi = 0; mi < 2; ++mi)
                a[mi] = *reinterpret_cast<const short8*>(Cm + base + (size_t)(w * 32 + mi * 16 + fr) * 2048 + hk * 64 + ks * 32 + fk);
#pragma unroll
            for (int ni = 0; ni < 8; ++ni)
                bfr[ni] = *reinterpret_cast<const short8*>(&T1[ni * 16 + fr][ks * 32 + fk]);
#pragma unroll
            for (int mi = 0; mi < 2; ++mi)
#pragma unroll
                for (int ni = 0; ni < 8; ++ni)
                    acc[mi][ni] = __builtin_amdgcn_mfma_f32_16x16x32_bf16(a[mi], bfr[ni], acc[mi][ni], 0, 0, 0);
        }
        __builtin_amdgcn_s_setprio(0);
        __syncthreads();
    }
    // scale by decay_out = dec^(i+1)
#pragma unroll
    for (int mi = 0; mi < 2; ++mi)
#pragma unroll
        for (int r = 0; r < 4; ++r) {
            int i = w * 32 + mi * 16 + orow0 + r;
            float sc = exp2f((float)(i + 1) * l2d);
#pragma unroll
            for (int ni = 0; ni < 8; ++ni) acc[mi][ni][r] *= sc;
        }
    // ---- phase C: acc += P @ XDT (XDT halves staged through T1; A-op from Ps)
    for (int j0 = 0; j0 < 128; j0 += 64) {
        for (int rr = 0; rr < 128; rr += 32) {
            int row = rr + strow;
            *reinterpret_cast<short8*>(&T1[row][stcol]) =
                *reinterpret_cast<const short8*>(XDT + ob + (size_t)row * 128 + j0 + stcol);
        }
        __syncthreads();
        __builtin_amdgcn_s_setprio(1);
#pragma unroll
        for (int ks = 0; ks < 2; ++ks) {
            short8 a[2], bfr[8];
#pragma unroll
            for (int mi = 0; mi < 2; ++mi)
                a[mi] = *reinterpret_cast<const short8*>(&Ps[w * 32 + mi * 16 + fr][j0 + ks * 32 + fk]);
#pragma unroll
            for (int ni = 0; ni < 8; ++ni)
                bfr[ni] = *reinterpret_cast<const short8*>(&T1[ni * 16 + fr][ks * 32 + fk]);
#pragma unroll
            for (int mi = 0; mi < 2; ++mi)
#pragma unroll
                for (int ni = 0; ni < 8; ++ni)
                    acc[mi][ni] = __builtin_amdgcn_mfma_f32_16x16x32_bf16(a[mi], bfr[ni], acc[mi][ni], 0, 0, 0);
        }
        __builtin_amdgcn_s_setprio(0);
        __syncthreads();
    }
    // ---- epilogue: y = (acc + D*v) * silu(gate); v = XDT[d][i]/dt
    const float Dv = D_param[h];
    const float inv_dt = 1.f / dt;
#pragma unroll
    for (int mi = 0; mi < 2; ++mi)
#pragma unroll
        for (int ni = 0; ni < 8; ++ni) {
            int d = ni * 16 + ocol;
#pragma unroll
            for (int r = 0; r < 4; ++r) {
                int i = w * 32 + mi * 16 + orow0 + r;
                size_t idx = base + (size_t)i * 2048 + d;
                float v = bf2f(XDT[ob + (size_t)d * 128 + i]) * inv_dt;
                float yv = acc[mi][ni][r] + Dv * v;
                float gq = bf2f(gateY[idx]);
                gateY[idx] = f2bf(yv * gq / (1.f + expf(-gq)));
            }
        }
}

extern "C" void kernel_launch(void* const* d_in, const int* in_sizes, int n_in,
                              void* d_out, int out_size, void* d_ws, size_t ws_size,
                              hipStream_t stream) {
    (void)out_size;
    static const int exp_sizes[11] = {
        NB * LSEQ * DM, NB * LSEQ * DM, 2 * DI * DM, DI * 4, DI,
        NH * DSZ * DM, NH * DSZ * DM, NH, NH, NH, DM * DI
    };
    if (n_in != 11) return;
    for (int i = 0; i < 11; ++i) if (in_sizes[i] != exp_sizes[i]) return;

    const float* x         = (const float*)d_in[0];
    const float* x_prenorm = (const float*)d_in[1];
    const float* in_proj_w = (const float*)d_in[2];
    const float* conv_w    = (const float*)d_in[3];
    const float* conv_b    = (const float*)d_in[4];
    const float* B_proj_w  = (const float*)d_in[5];
    const float* C_proj_w  = (const float*)d_in[6];
    const float* dt_bias   = (const float*)d_in[7];
    const float* A_log     = (const float*)d_in[8];
    const float* D_param   = (const float*)d_in[9];
    const float* out_proj_w= (const float*)d_in[10];
    float* out = (float*)d_out;

    const size_t NE = (size_t)NB * LSEQ * DI;     // 16,777,216 elements
    const size_t SLOT = NE * 2;                   // 32 MiB
    if (ws_size < 5 * SLOT) return;               // 160 MiB (verified available)
    char* ws = (char*)d_ws;
    bf16* S0 = (bf16*)(ws);              // value_pre -> BT -> STT (in place)
    bf16* S1 = (bf16*)(ws + SLOT);       // gate -> y (in place)
    bf16* S2 = (bf16*)(ws + 2 * SLOT);   // XDT
    bf16* S3 = (bf16*)(ws + 3 * SLOT);   // w_in_b -> Bm -> w_out_b
    bf16* S4 = (bf16*)(ws + 4 * SLOT);   // Cm

    // d_out scratch: [xb | wBCb] until BC gemm done; then free until final output
    bf16* xb   = (bf16*)d_out;                         // 16.8 MB
    bf16* wBCb = (bf16*)((char*)d_out + 16777216);     // 8.4 MB

    const int M = NB * LSEQ;             // 8192
    const int NC = NB * NCHUNK * NH;     // 1024 chunk-blocks
    dim3 blk(256);

    // phase 1: in_proj
    cast_f2b<<<dim3(4096), blk, 0, stream>>>(x, xb, (long)NB * LSEQ * DM);
    cast_f2b<<<dim3(2048), blk, 0, stream>>>(in_proj_w, S3, (long)2 * DI * DM);
    gemm_mfma<1, bf16><<<dim3(2 * DI / 128, M / 128), blk, 0, stream>>>(xb, S3, S0, S1, 2 * DI, DM);
    // phase 2: fused conv+silu+dt+transpose -> XDT (S2); S0 (vpre) dead after
    conv_xdt<<<dim3(NC), blk, 0, stream>>>(S0, conv_w, conv_b, dt_bias, S2);
    // phase 3: merged B+C projection -> Bm (S3), Cm (S4)
    cast_f2b<<<dim3(4096), blk, 0, stream>>>(x_prenorm, xb, (long)NB * LSEQ * DM);
    cast_f2b<<<dim3(1024), blk, 0, stream>>>(B_proj_w, wBCb, (long)NH * DSZ * DM);
    cast_f2b<<<dim3(1024), blk, 0, stream>>>(C_proj_w, wBCb + (size_t)NH * DSZ * DM, (long)NH * DSZ * DM);
    gemm_mfma<1, bf16><<<dim3(2 * DI / 128, M / 128), blk, 0, stream>>>(xb, wBCb, S3, S4, 2 * DI, DM);
    // phase 3b: BT = scaled transpose of Bm -> S0 (coalesced LDS transpose)
    transpose_bt<<<dim3(NC), blk, 0, stream>>>(S3, S0, dt_bias, A_log);
    // phase 4: states (BT -> STT in place), inter-chunk scan
    chunk_statesT<<<dim3(NC), blk, 0, stream>>>(S2, S0, S0);
    scan_kernel<<<dim3(NB * NH * 8), blk, 0, stream>>>(S0, dt_bias, A_log);
    // phase 5: merged cbl + y -> y over gate (S1)
    chunk_cbl_y<<<dim3(NC), blk, 0, stream>>>(S3, S4, S0, S2, dt_bias, A_log, D_param, S1);
    // phase 6: out_proj -> f32 d_out
    cast_f2b<<<dim3(1024), blk, 0, stream>>>(out_proj_w, S3, (long)DM * DI);
    gemm_mfma<2, float><<<dim3(DM / 128, M / 128), blk, 0, stream>>>(S1, S3, out, nullptr, DM, DI);
}

// Round 18
// 372.917 us; speedup vs baseline: 1.1799x; 1.0343x over previous
//
#include <hip/hip_runtime.h>
#include <hip/hip_bf16.h>

// Mamba2 mixer forward, MI355X gfx950. Round 18: r17 + BT transpose folded into
// BC-GEMM epilogue via LDS union tile (kills transpose_bt dispatch + 67MB HBM),
// merged phase-3 casts. GEMM K-loop and all other kernels frozen from r17.
// Shapes fixed: B=2 L=4096 dm=1024 di=2048 H=16 ds=hd=128 cs=128
#define NB 2
#define LSEQ 4096
#define DM 1024
#define DI 2048
#define NH 16
#define DSZ 128
#define CS 128
#define NCHUNK 32

using bf16 = __hip_bfloat16;
typedef __attribute__((ext_vector_type(8))) short short8;
typedef __attribute__((ext_vector_type(4))) float f32x4;

__device__ __forceinline__ float b2f(unsigned short u) {
    union { unsigned i; float f; } c; c.i = ((unsigned)u) << 16; return c.f;
}
__device__ __forceinline__ bf16 f2bf(float v) { return __float2bfloat16(v); }
__device__ __forceinline__ float bf2f(bf16 v) { return __bfloat162float(v); }

__device__ __forceinline__ float head_dt(const float* dt_bias, int h) {
    return log1pf(expf(dt_bias[h]));               // softplus
}
__device__ __forceinline__ float head_l2dec(const float* dt_bias, const float* A_log, int h, float* dt_out) {
    float dt = head_dt(dt_bias, h);
    *dt_out = dt;
    return -expf(A_log[h]) * dt * 1.4426950408889634f;   // log2(decay)
}

__device__ __forceinline__ void storeC(bf16* C, size_t idx, float v) { C[idx] = f2bf(v); }
__device__ __forceinline__ void storeC(float* C, size_t idx, float v) { C[idx] = v; }

// async global->LDS, 16B per lane; lds base wave-uniform (HW adds lane*16B)
__device__ __forceinline__ void gload16(const bf16* g, bf16* l) {
    __builtin_amdgcn_global_load_lds(
        (const __attribute__((address_space(1))) void*)g,
        (__attribute__((address_space(3))) void*)l, 16, 0, 0);
}

// ---------------- f32 -> bf16 cast (single buffer)
__global__ __launch_bounds__(256) void cast_f2b(const float* __restrict__ in,
                                                bf16* __restrict__ out, long n) {
    long i = ((long)blockIdx.x * 256 + threadIdx.x) * 8;
    if (i >= n) return;
    float4 a = *reinterpret_cast<const float4*>(in + i);
    float4 b = *reinterpret_cast<const float4*>(in + i + 4);
    union { bf16 h[8]; short8 v; } o;
    o.h[0] = f2bf(a.x); o.h[1] = f2bf(a.y); o.h[2] = f2bf(a.z); o.h[3] = f2bf(a.w);
    o.h[4] = f2bf(b.x); o.h[5] = f2bf(b.y); o.h[6] = f2bf(b.z); o.h[7] = f2bf(b.w);
    *reinterpret_cast<short8*>(out + i) = o.v;
}

// ---------------- f32 -> bf16 cast, three buffers in one dispatch
__global__ __launch_bounds__(256) void cast3_f2b(const float* __restrict__ a, bf16* __restrict__ da, long na,
                                                 const float* __restrict__ b, bf16* __restrict__ db, long nb,
                                                 const float* __restrict__ c, bf16* __restrict__ dc, long nc) {
    long i = ((long)blockIdx.x * 256 + threadIdx.x) * 8;
    const float* src; bf16* dst; long off;
    if (i < na)            { src = a; dst = da; off = i; }
    else if (i < na + nb)  { src = b; dst = db; off = i - na; }
    else if (i < na + nb + nc) { src = c; dst = dc; off = i - na - nb; }
    else return;
    float4 x = *reinterpret_cast<const float4*>(src + off);
    float4 y = *reinterpret_cast<const float4*>(src + off + 4);
    union { bf16 h[8]; short8 v; } o;
    o.h[0] = f2bf(x.x); o.h[1] = f2bf(x.y); o.h[2] = f2bf(x.z); o.h[3] = f2bf(x.w);
    o.h[4] = f2bf(y.x); o.h[5] = f2bf(y.y); o.h[6] = f2bf(y.z); o.h[7] = f2bf(y.w);
    *reinterpret_cast<short8*>(dst + off) = o.v;
}

// ---------------- 128x128 MFMA GEMM (r9/r12-verified K-loop, linear block map).
// MODE 1: col<DI->C0 else C1. MODE 2: C0[m*N+n].
// MODE 3: MODE 1 + (for blocks with bn<DI) BT[s][j]=acc*dec^(127-j) via LDS
//         transpose into C2 (per-block (chunk=blockIdx.y, head=blockIdx.x) tile).
template <int MODE, typename TO>
__global__ __launch_bounds__(256) void gemm_mfma(const bf16* __restrict__ A,
                                                 const bf16* __restrict__ W,
                                                 TO* __restrict__ C0, TO* __restrict__ C1,
                                                 bf16* __restrict__ C2,
                                                 const float* dt_bias, const float* A_log,
                                                 int N, int K) {
    __shared__ char smem[35328];                       // As(16K)+Ws(16K) | TP(34816) ; dpw @34816
    bf16* Asb = reinterpret_cast<bf16*>(smem);         // [2][128*32] linear
    bf16* Wsb = reinterpret_cast<bf16*>(smem + 16384);
    bf16 (*TP)[136] = reinterpret_cast<bf16(*)[136]>(smem);   // aliases As+Ws (epilogue only)
    float* dpw = reinterpret_cast<float*>(smem + 34816);      // [128], disjoint
    const int tid = threadIdx.x;
    const int lane = tid & 63, w = tid >> 6;
    const int wr = w >> 1, wc = w & 1;
    const int bm = blockIdx.y * 128, bn = blockIdx.x * 128;
    const int srow = lane >> 2;
    const int skoff = (((lane & 3) ^ ((lane >> 2) & 3)) * 8);
    const int g0 = w * 2, g1 = w * 2 + 1;
    const int fr = lane & 15;
    const int fk = (((lane >> 4) ^ (lane & 3)) * 8);
    if (MODE == 3 && bn < DI && tid < 128) {
        float dtq;
        float l2d = head_l2dec(dt_bias, A_log, blockIdx.x & 15, &dtq);
        dpw[tid] = exp2f((float)(127 - tid) * l2d);
    }
    f32x4 acc[4][4] = {};
#define STAGE(buf, kt)                                                                        \
    do {                                                                                      \
        gload16(A + (size_t)(bm + g0 * 16 + srow) * K + (kt) + skoff, Asb + (buf) * 4096 + g0 * 512); \
        gload16(A + (size_t)(bm + g1 * 16 + srow) * K + (kt) + skoff, Asb + (buf) * 4096 + g1 * 512); \
        gload16(W + (size_t)(bn + g0 * 16 + srow) * K + (kt) + skoff, Wsb + (buf) * 4096 + g0 * 512); \
        gload16(W + (size_t)(bn + g1 * 16 + srow) * K + (kt) + skoff, Wsb + (buf) * 4096 + g1 * 512); \
    } while (0)
    STAGE(0, 0);
    __syncthreads();
    const int NT = K / 32;
    int cur = 0;
    for (int t = 0; t < NT; ++t) {
        if (t + 1 < NT) STAGE(cur ^ 1, (t + 1) * 32);
        short8 af[4], bfr[4];
#pragma unroll
        for (int mi = 0; mi < 4; ++mi)
            af[mi] = *reinterpret_cast<const short8*>(Asb + cur * 4096 + (wr * 64 + mi * 16 + fr) * 32 + fk);
#pragma unroll
        for (int ni = 0; ni < 4; ++ni)
            bfr[ni] = *reinterpret_cast<const short8*>(Wsb + cur * 4096 + (wc * 64 + ni * 16 + fr) * 32 + fk);
#pragma unroll
        for (int mi = 0; mi < 4; ++mi)
#pragma unroll
            for (int ni = 0; ni < 4; ++ni)
                acc[mi][ni] = __builtin_amdgcn_mfma_f32_16x16x32_bf16(af[mi], bfr[ni], acc[mi][ni], 0, 0, 0);
        __syncthreads();
        cur ^= 1;
    }
#undef STAGE
    const int orow0 = (lane >> 4) * 4;
    const int ocol = lane & 15;
#pragma unroll
    for (int mi = 0; mi < 4; ++mi)
#pragma unroll
        for (int ni = 0; ni < 4; ++ni) {
            int col = bn + wc * 64 + ni * 16 + ocol;
#pragma unroll
            for (int r = 0; r < 4; ++r) {
                int row = bm + wr * 64 + mi * 16 + orow0 + r;
                float v = acc[mi][ni][r];
                if (MODE == 1 || MODE == 3) {
                    if (col < DI) storeC(C0, (size_t)row * DI + col, v);
                    else          storeC(C1, (size_t)row * DI + (col - DI), v);
                } else {
                    storeC(C0, (size_t)row * N + col, v);
                }
            }
        }
    // ---- MODE 3: BT tile via LDS transpose (only B-column blocks)
    if (MODE == 3 && bn < DI) {
        __syncthreads();          // K-loop LDS reads done in ALL waves; dpw visible
        // scatter acc -> TP[s_local][j_local] (8B per frag: 4 consecutive j)
#pragma unroll
        for (int mi = 0; mi < 4; ++mi) {
            int j0l = wr * 64 + mi * 16 + orow0;
#pragma unroll
            for (int ni = 0; ni < 4; ++ni) {
                int sl = wc * 64 + ni * 16 + ocol;
                bf16 tmp[4];
#pragma unroll
                for (int r = 0; r < 4; ++r) tmp[r] = f2bf(acc[mi][ni][r]);
                *reinterpret_cast<uint2*>(&TP[sl][j0l]) = *reinterpret_cast<const uint2*>(tmp);
            }
        }
        __syncthreads();
        // coalesced scaled write: row s = tid>>1, 64 cols per half
        const size_t btb = ((size_t)blockIdx.y * 16 + (blockIdx.x & 15)) * 16384;
        const int s = tid >> 1;
        const int jh = (tid & 1) * 64;
#pragma unroll
        for (int gq = 0; gq < 8; ++gq) {
            int j = jh + gq * 8;
            union { bf16 hh[8]; short8 v; } o;
#pragma unroll
            for (int e = 0; e < 8; ++e) o.hh[e] = f2bf(bf2f(TP[s][j + e]) * dpw[j + e]);
            *reinterpret_cast<short8*>(C2 + btb + (size_t)s * 128 + j) = o.v;
        }
    }
}

// ---------------- fused conv(K=4)+bias+SiLU+*dt+transpose -> XDT[d][j] (frozen r12)
__global__ __launch_bounds__(256) void conv_xdt(const bf16* __restrict__ vpre,
                                                const float* __restrict__ cw,
                                                const float* __restrict__ cb,
                                                const float* __restrict__ dt_bias,
                                                bf16* __restrict__ XDT) {
    __shared__ bf16 Ts[131][136];
    __shared__ bf16 T2[128][136];
    __shared__ float wks[128][4];
    __shared__ float cbs[128];
    const int tid = threadIdx.x;
    const int bid = blockIdx.x;            // g*16 + h
    const int h = bid & 15, g = bid >> 4;  // g = b*32+n
    const int n31 = g & 31;
    const float dt = head_dt(dt_bias, h);
    if (tid < 128) {
        float4 w4 = *reinterpret_cast<const float4*>(cw + (h * 128 + tid) * 4);
        wks[tid][0] = w4.x; wks[tid][1] = w4.y; wks[tid][2] = w4.z; wks[tid][3] = w4.w;
        cbs[tid] = cb[h * 128 + tid];
    }
    {
        const int lr = tid >> 4, c8 = (tid & 15) * 8;
        for (int i0 = 0; i0 < 144; i0 += 16) {
            int i = i0 + lr;
            if (i < 131) {
                short8 v = {0, 0, 0, 0, 0, 0, 0, 0};
                if (!(n31 == 0 && i < 3))
                    v = *reinterpret_cast<const short8*>(vpre + (size_t)(g * 128 - 3 + i) * 2048 + h * 128 + c8);
                *reinterpret_cast<short8*>(&Ts[i][c8]) = v;
            }
        }
    }
    __syncthreads();
    {
        const int jr = tid >> 4, d8 = (tid & 15) * 8;
        for (int j0 = 0; j0 < 128; j0 += 16) {
            int j = j0 + jr;
            union { bf16 hh[8]; short8 v; } o;
#pragma unroll
            for (int e = 0; e < 8; ++e) {
                int d = d8 + e;
                float s = cbs[d];
#pragma unroll
                for (int k = 0; k < 4; ++k) s += wks[d][k] * bf2f(Ts[j + k][d]);
                float sil = s / (1.f + expf(-s));
                o.hh[e] = f2bf(sil * dt);
            }
            *reinterpret_cast<short8*>(&T2[j][d8]) = o.v;
        }
    }
    __syncthreads();
    {
        const size_t ob = (size_t)bid * 16384;
        const int d = tid & 127;
        for (int jg = (tid >> 7); jg < 16; jg += 2) {
            int j0 = jg * 8;
            union { bf16 hh[8]; short8 v; } o;
#pragma unroll
            for (int e = 0; e < 8; ++e) o.hh[e] = T2[j0 + e][d];
            *reinterpret_cast<short8*>(XDT + ob + (size_t)d * 128 + j0) = o.v;
        }
    }
}

// ---------------- K1: STT[d][s] = sum_j XDT[d][j] * BT[s][j]  (+T5 setprio; STT may alias BT)
__global__ __launch_bounds__(256) void chunk_statesT(const bf16* __restrict__ XDT,
                                                     const bf16* BTg,
                                                     bf16* STT) {
    __shared__ bf16 XTs[128][72];
    __shared__ bf16 BTs[128][72];
    const int tid = threadIdx.x;
    const size_t ob = (size_t)blockIdx.x * 16384;
    const int lane = tid & 63, w = tid >> 6;
    const int fr = lane & 15, fk = (lane >> 4) * 8;
    f32x4 acc[2][8] = {};
    for (int j0 = 0; j0 < 128; j0 += 64) {
        for (int rr = 0; rr < 128; rr += 32) {
            int row = rr + (tid >> 3);
            int col = (tid & 7) * 8;
            *reinterpret_cast<short8*>(&XTs[row][col]) =
                *reinterpret_cast<const short8*>(XDT + ob + (size_t)row * 128 + j0 + col);
            *reinterpret_cast<short8*>(&BTs[row][col]) =
                *reinterpret_cast<const short8*>(BTg + ob + (size_t)row * 128 + j0 + col);
        }
        __syncthreads();
        __builtin_amdgcn_s_setprio(1);
#pragma unroll
        for (int ks = 0; ks < 2; ++ks) {
            short8 a[2], bfr[8];
#pragma unroll
            for (int mi = 0; mi < 2; ++mi)
                a[mi] = *reinterpret_cast<const short8*>(&XTs[w * 32 + mi * 16 + fr][ks * 32 + fk]);
#pragma unroll
            for (int ni = 0; ni < 8; ++ni)
                bfr[ni] = *reinterpret_cast<const short8*>(&BTs[ni * 16 + fr][ks * 32 + fk]);
#pragma unroll
            for (int mi = 0; mi < 2; ++mi)
#pragma unroll
                for (int ni = 0; ni < 8; ++ni)
                    acc[mi][ni] = __builtin_amdgcn_mfma_f32_16x16x32_bf16(a[mi], bfr[ni], acc[mi][ni], 0, 0, 0);
        }
        __builtin_amdgcn_s_setprio(0);
        __syncthreads();
    }
    const int orow0 = (lane >> 4) * 4, ocol = lane & 15;
#pragma unroll
    for (int mi = 0; mi < 2; ++mi)
#pragma unroll
        for (int ni = 0; ni < 8; ++ni) {
            int s = ni * 16 + ocol;
#pragma unroll
            for (int r = 0; r < 4; ++r) {
                int d = w * 32 + mi * 16 + orow0 + r;
                STT[ob + (size_t)d * 128 + s] = f2bf(acc[mi][ni][r]);
            }
        }
}

// ---------------- inter-chunk recurrence on STT (frozen r12)
__global__ __launch_bounds__(256) void scan_kernel(bf16* __restrict__ ST,
                                                   const float* __restrict__ dt_bias,
                                                   const float* __restrict__ A_log) {
    const int q = blockIdx.x & 7;
    const int h = (blockIdx.x >> 3) & 15;
    const int b = blockIdx.x >> 7;
    float dt; float l2d = head_l2dec(dt_bias, A_log, h, &dt);
    float cd = exp2f(128.f * l2d);
    const int tid = threadIdx.x;
    float r[8] = {};
    for (int n = 0; n < NCHUNK; ++n) {
        size_t base = ((size_t)((b * NCHUNK + n) * NH + h)) * 16384 + (size_t)q * 2048;
#pragma unroll
        for (int e = 0; e < 8; ++e) {
            size_t idx = base + e * 256 + tid;
            float v = bf2f(ST[idx]);
            ST[idx] = f2bf(r[e]);
            r[e] = cd * r[e] + v;
        }
    }
}

// ---------------- merged: P = mask(C B^T); y = P@XDT + (C@STT)*dec^(i+1) + D*v; *silu(gate)
// r17 structure (STT/XDT staged via T1, T5 setprio).
__global__ __launch_bounds__(256) void chunk_cbl_y(const bf16* __restrict__ Bm, const bf16* __restrict__ Cm,
                                                   const bf16* __restrict__ STT, const bf16* __restrict__ XDT,
                                                   const float* __restrict__ dt_bias,
                                                   const float* __restrict__ A_log,
                                                   const float* __restrict__ D_param,
                                                   bf16* __restrict__ gateY) {
    __shared__ char smem[53248];
    bf16 (*T1)[72]  = reinterpret_cast<bf16(*)[72]>(smem);
    bf16 (*Ps)[136] = reinterpret_cast<bf16(*)[136]>(smem + 18432);
    bf16 (*Bst)[72] = reinterpret_cast<bf16(*)[72]>(smem + 18432);
    const int tid = threadIdx.x;
    const int bid = blockIdx.x;
    const int h = bid & 15, g = bid >> 4;
    float dt; float l2d = head_l2dec(dt_bias, A_log, h, &dt);
    const size_t base = (size_t)g * CS * 2048 + (size_t)h * 128;
    const size_t ob = (size_t)bid * 16384;
    const int lane = tid & 63, w = tid >> 6;
    const int fr = lane & 15, fk = (lane >> 4) * 8;
    const int orow0 = (lane >> 4) * 4, ocol = lane & 15;
    const int strow = tid >> 3, stcol = (tid & 7) * 8;
    f32x4 pacc[2][8] = {};
    for (int s0 = 0; s0 < 128; s0 += 64) {
        for (int rr = 0; rr < 128; rr += 32) {
            int row = rr + strow;
            *reinterpret_cast<short8*>(&T1[row][stcol]) =
                *reinterpret_cast<const short8*>(Cm + base + (size_t)row * 2048 + s0 + stcol);
            *reinterpret_cast<short8*>(&Bst[row][stcol]) =
                *reinterpret_cast<const short8*>(Bm + base + (size_t)row * 2048 + s0 + stcol);
        }
        __syncthreads();
        __builtin_amdgcn_s_setprio(1);
#pragma unroll
        for (int ks = 0; ks < 2; ++ks) {
            short8 a[2], bfr[8];
#pragma unroll
            for (int mi = 0; mi < 2; ++mi)
                a[mi] = *reinterpret_cast<const short8*>(&T1[w * 32 + mi * 16 + fr][ks * 32 + fk]);
#pragma unroll
            for (int ni = 0; ni < 8; ++ni)
                bfr[ni] = *reinterpret_cast<const short8*>(&Bst[ni * 16 + fr][ks * 32 + fk]);
#pragma unroll
            for (int mi = 0; mi < 2; ++mi)
#pragma unroll
                for (int ni = 0; ni < 8; ++ni)
                    pacc[mi][ni] = __builtin_amdgcn_mfma_f32_16x16x32_bf16(a[mi], bfr[ni], pacc[mi][ni], 0, 0, 0);
        }
        __builtin_amdgcn_s_setprio(0);
        __syncthreads();
    }
#pragma unroll
    for (int mi = 0; mi < 2; ++mi)
#pragma unroll
        for (int ni = 0; ni < 8; ++ni) {
            int j = ni * 16 + ocol;
#pragma unroll
            for (int r = 0; r < 4; ++r) {
                int i = w * 32 + mi * 16 + orow0 + r;
                float v = (i >= j) ? pacc[mi][ni][r] * exp2f((float)(i - j) * l2d) : 0.f;
                Ps[i][j] = f2bf(v);
            }
        }
    f32x4 acc[2][8] = {};
    for (int hk = 0; hk < 2; ++hk) {
        for (int rr = 0; rr < 128; rr += 32) {
            int row = rr + strow;
            *reinterpret_cast<short8*>(&T1[row][stcol]) =
                *reinterpret_cast<const short8*>(STT + ob + (size_t)row * 128 + hk * 64 + stcol);
        }
        __syncthreads();
        __builtin_amdgcn_s_setprio(1);
#pragma unroll
        for (int ks = 0; ks < 2; ++ks) {
            short8 a[2], bfr[8];
#pragma unroll
            for (int mi = 0; mi < 2; ++mi)
                a[mi] = *reinterpret_cast<const short8*>(Cm + base + (size_t)(w * 32 + mi * 16 + fr) * 2048 + hk * 64 + ks * 32 + fk);
#pragma unroll
            for (int ni = 0; ni < 8; ++ni)
                bfr[ni] = *reinterpret_cast<const short8*>(&T1[ni * 16 + fr][ks * 32 + fk]);
#pragma unroll
            for (int mi = 0; mi < 2; ++mi)
#pragma unroll
                for (int ni = 0; ni < 8; ++ni)
                    acc[mi][ni] = __builtin_amdgcn_mfma_f32_16x16x32_bf16(a[mi], bfr[ni], acc[mi][ni], 0, 0, 0);
        }
        __builtin_amdgcn_s_setprio(0);
        __syncthreads();
    }
#pragma unroll
    for (int mi = 0; mi < 2; ++mi)
#pragma unroll
        for (int r = 0; r < 4; ++r) {
            int i = w * 32 + mi * 16 + orow0 + r;
            float sc = exp2f((float)(i + 1) * l2d);
#pragma unroll
            for (int ni = 0; ni < 8; ++ni) acc[mi][ni][r] *= sc;
        }
    for (int j0 = 0; j0 < 128; j0 += 64) {
        for (int rr = 0; rr < 128; rr += 32) {
            int row = rr + strow;
            *reinterpret_cast<short8*>(&T1[row][stcol]) =
                *reinterpret_cast<const short8*>(XDT + ob + (size_t)row * 128 + j0 + stcol);
        }
        __syncthreads();
        __builtin_amdgcn_s_setprio(1);
#pragma unroll
        for (int ks = 0; ks < 2; ++ks) {
            short8 a[2], bfr[8];
#pragma unroll
            for (int mi = 0; mi < 2; ++mi)
                a[mi] = *reinterpret_cast<const short8*>(&Ps[w * 32 + mi * 16 + fr][j0 + ks * 32 + fk]);
#pragma unroll
            for (int ni = 0; ni < 8; ++ni)
                bfr[ni] = *reinterpret_cast<const short8*>(&T1[ni * 16 + fr][ks * 32 + fk]);
#pragma unroll
            for (int mi = 0; mi < 2; ++mi)
#pragma unroll
                for (int ni = 0; ni < 8; ++ni)
                    acc[mi][ni] = __builtin_amdgcn_mfma_f32_16x16x32_bf16(a[mi], bfr[ni], acc[mi][ni], 0, 0, 0);
        }
        __builtin_amdgcn_s_setprio(0);
        __syncthreads();
    }
    const float Dv = D_param[h];
    const float inv_dt = 1.f / dt;
#pragma unroll
    for (int mi = 0; mi < 2; ++mi)
#pragma unroll
        for (int ni = 0; ni < 8; ++ni) {
            int d = ni * 16 + ocol;
#pragma unroll
            for (int r = 0; r < 4; ++r) {
                int i = w * 32 + mi * 16 + orow0 + r;
                size_t idx = base + (size_t)i * 2048 + d;
                float v = bf2f(XDT[ob + (size_t)d * 128 + i]) * inv_dt;
                float yv = acc[mi][ni][r] + Dv * v;
                float gq = bf2f(gateY[idx]);
                gateY[idx] = f2bf(yv * gq / (1.f + expf(-gq)));
            }
        }
}

extern "C" void kernel_launch(void* const* d_in, const int* in_sizes, int n_in,
                              void* d_out, int out_size, void* d_ws, size_t ws_size,
                              hipStream_t stream) {
    (void)out_size;
    static const int exp_sizes[11] = {
        NB * LSEQ * DM, NB * LSEQ * DM, 2 * DI * DM, DI * 4, DI,
        NH * DSZ * DM, NH * DSZ * DM, NH, NH, NH, DM * DI
    };
    if (n_in != 11) return;
    for (int i = 0; i < 11; ++i) if (in_sizes[i] != exp_sizes[i]) return;

    const float* x         = (const float*)d_in[0];
    const float* x_prenorm = (const float*)d_in[1];
    const float* in_proj_w = (const float*)d_in[2];
    const float* conv_w    = (const float*)d_in[3];
    const float* conv_b    = (const float*)d_in[4];
    const float* B_proj_w  = (const float*)d_in[5];
    const float* C_proj_w  = (const float*)d_in[6];
    const float* dt_bias   = (const float*)d_in[7];
    const float* A_log     = (const float*)d_in[8];
    const float* D_param   = (const float*)d_in[9];
    const float* out_proj_w= (const float*)d_in[10];
    float* out = (float*)d_out;

    const size_t NE = (size_t)NB * LSEQ * DI;     // 16,777,216 elements
    const size_t SLOT = NE * 2;                   // 32 MiB
    if (ws_size < 5 * SLOT) return;               // 160 MiB (verified available)
    char* ws = (char*)d_ws;
    bf16* S0 = (bf16*)(ws);              // value_pre -> BT -> STT (in place)
    bf16* S1 = (bf16*)(ws + SLOT);       // gate -> y (in place)
    bf16* S2 = (bf16*)(ws + 2 * SLOT);   // XDT
    bf16* S3 = (bf16*)(ws + 3 * SLOT);   // w_in_b -> Bm -> w_out_b
    bf16* S4 = (bf16*)(ws + 4 * SLOT);   // Cm

    bf16* xb   = (bf16*)d_out;                         // 16.8 MB scratch
    bf16* wBCb = (bf16*)((char*)d_out + 16777216);     // 8.4 MB scratch

    const int M = NB * LSEQ;             // 8192
    const int NC = NB * NCHUNK * NH;     // 1024 chunk-blocks
    dim3 blk(256);
    const long nXP = (long)NB * LSEQ * DM;          // 8388608
    const long nW  = (long)NH * DSZ * DM;           // 2097152

    // phase 1: in_proj
    cast_f2b<<<dim3(4096), blk, 0, stream>>>(x, xb, nXP);
    cast_f2b<<<dim3(2048), blk, 0, stream>>>(in_proj_w, S3, (long)2 * DI * DM);
    gemm_mfma<1, bf16><<<dim3(2 * DI / 128, M / 128), blk, 0, stream>>>(
        xb, S3, S0, S1, nullptr, nullptr, nullptr, 2 * DI, DM);
    // phase 2: fused conv+silu+dt+transpose -> XDT (S2); S0 (vpre) dead after
    conv_xdt<<<dim3(NC), blk, 0, stream>>>(S0, conv_w, conv_b, dt_bias, S2);
    // phase 3: merged B+C projection -> Bm (S3), Cm (S4), BT (S0 via epilogue)
    cast3_f2b<<<dim3(6144), blk, 0, stream>>>(x_prenorm, xb, nXP,
                                              B_proj_w, wBCb, nW,
                                              C_proj_w, wBCb + nW, nW);
    gemm_mfma<3, bf16><<<dim3(2 * DI / 128, M / 128), blk, 0, stream>>>(
        xb, wBCb, S3, S4, S0, dt_bias, A_log, 2 * DI, DM);
    // phase 4: states (BT -> STT in place), inter-chunk scan
    chunk_statesT<<<dim3(NC), blk, 0, stream>>>(S2, S0, S0);
    scan_kernel<<<dim3(NB * NH * 8), blk, 0, stream>>>(S0, dt_bias, A_log);
    // phase 5: merged cbl + y -> y over gate (S1)
    chunk_cbl_y<<<dim3(NC), blk, 0, stream>>>(S3, S4, S0, S2, dt_bias, A_log, D_param, S1);
    // phase 6: out_proj -> f32 d_out
    cast_f2b<<<dim3(1024), blk, 0, stream>>>(out_proj_w, S3, (long)DM * DI);
    gemm_mfma<2, float><<<dim3(DM / 128, M / 128), blk, 0, stream>>>(
        S1, S3, out, nullptr, nullptr, nullptr, nullptr, DM, DI);
}